// Round 6
// baseline (3333.824 us; speedup 1.0000x reference)
//
#include <hip/hip_runtime.h>

// ---------------------------------------------------------------------------
// VQ-VAE forward: bf16 MFMA implicit-GEMM convs (NHWC) + split-bf16 MFMA VQ.
// R6: non-temporal activation staging/stores (protect weights in L2) and
// split-CIN two-phase staging for CIN=128 convs (2x occupancy).
// ---------------------------------------------------------------------------

typedef float    f32x4  __attribute__((ext_vector_type(4)));
typedef short    bf16x8 __attribute__((ext_vector_type(8)));
typedef int      i32x4  __attribute__((ext_vector_type(4)));
typedef short    s16x4  __attribute__((ext_vector_type(4)));
typedef unsigned short ush;
typedef unsigned long long u64;

__device__ __forceinline__ ush f2bf(float f) {
    unsigned u = __float_as_uint(f);
    u += 0x7fff + ((u >> 16) & 1);          // round-to-nearest-even
    return (ush)(u >> 16);
}
__device__ __forceinline__ float bf2f(ush h) {
    return __uint_as_float(((unsigned)h) << 16);
}
__device__ __forceinline__ i32x4 ntld4(const void* p) {
    return __builtin_nontemporal_load((const i32x4*)p);
}

// ===================== weight repack OIHW f32 -> K-major bf16 ==============
__global__ void prep_w(const float* __restrict__ src, ush* __restrict__ dst,
                       int O, int I, int KS, int Opad)
{
    int idx = blockIdx.x * 256 + threadIdx.x;
    int K = KS * KS * I;
    if (idx >= Opad * K) return;
    int o = idx / K, k = idx - o * K;
    float v = 0.f;
    if (o < O) {
        int ci = k % I;
        int kxy = k / I;
        int kx = kxy % KS, ky = kxy / KS;
        v = src[((size_t)(o * I + ci) * KS + ky) * KS + kx];
    }
    dst[idx] = f2bf(v);
}

// ============ codebook split hi/lo, pre-swizzled LDS image =================
__global__ void prep_cb_split(const float* __restrict__ cb, char* __restrict__ img)
{
    int idx = blockIdx.x * 256 + threadIdx.x;   // 1024*128
    if (idx >= 1024 * 128) return;
    int k = idx >> 7, e = idx & 127;
    int chunk = k >> 7, cidx = k & 127;
    float c = cb[idx];
    ush hi = f2bf(c);
    ush lo = f2bf(c - bf2f(hi));
    int boff = (((cidx * 128) + e) * 2) ^ ((cidx & 7) << 4);
    char* base = img + (size_t)chunk * 65536;
    *(ush*)(base + boff) = hi;
    *(ush*)(base + boff + 32768) = lo;
}

// ===================== enc_in: 3->64, NCHW f32 in -> NHWC bf16 out =========
__global__ __launch_bounds__(256) void enc_in_k(
    const float* __restrict__ x, const float* __restrict__ w,
    const float* __restrict__ bias, ush* __restrict__ out)
{
    __shared__ float sX[3][3][260];
    __shared__ float sW[27][64];
    __shared__ float sB[64];
    const int tid = threadIdx.x;
    const int y = blockIdx.x, b = blockIdx.y;

    for (int i = tid; i < 3 * 3 * 258; i += 256) {
        int xi = i % 258;
        int r  = (i / 258) % 3;
        int c  = i / 774;
        int gy = y + r - 1, gx = xi - 1;
        float v = 0.f;
        if ((unsigned)gy < 256u && (unsigned)gx < 256u)
            v = x[(((size_t)b * 3 + c) * 256 + gy) * 256 + gx];
        sX[c][r][xi] = v;
    }
    for (int i = tid; i < 1728; i += 256) {
        int co = i & 63, k = i >> 6;
        int c = k % 3, kxy = k / 3;
        int kx = kxy % 3, ky = kxy / 3;
        sW[k][co] = w[co * 27 + c * 9 + ky * 3 + kx];
    }
    if (tid < 64) sB[tid] = bias[tid];
    __syncthreads();

    float acc[64];
#pragma unroll
    for (int c = 0; c < 64; ++c) acc[c] = 0.f;
    const int px = tid;
#pragma unroll
    for (int k = 0; k < 27; ++k) {
        const int c = k % 3, kxy = k / 3;
        const int kx = kxy % 3, ky = kxy / 3;
        float iv = sX[c][ky][px + kx];
#pragma unroll
        for (int co = 0; co < 64; ++co) acc[co] = fmaf(iv, sW[k][co], acc[co]);
    }
    ush* op = out + (((size_t)b * 256 + y) * 256 + px) * 64;
#pragma unroll
    for (int c8 = 0; c8 < 8; ++c8) {
        ush tmp[8];
#pragma unroll
        for (int j = 0; j < 8; ++j) tmp[j] = f2bf(acc[c8 * 8 + j] + sB[c8 * 8 + j]);
        *(int4*)(op + c8 * 8) = *(const int4*)tmp;
    }
}

// ===================== MFMA conv, stride 1, NHWC bf16 ======================
// Block: 64 cout x 64 px x ROWS rows, 4 waves. CIN>64 is processed in two
// ci-phases of 64 (halves LDS -> 2x occupancy). NT staging loads/stores.
template<int CIN, int COUT, int KS, int ROWS, bool RELU, bool ADD>
__global__ __launch_bounds__(256) void mconv(
    const ush* __restrict__ in, const ush* __restrict__ wt,
    const float* __restrict__ bias, const ush* __restrict__ res,
    ush* __restrict__ out, int H, int W)
{
    constexpr int HALO  = KS / 2;
    constexpr int XW    = 64 + 2 * HALO;
    constexpr int K     = KS * KS * CIN;
    constexpr int COB   = COUT / 64;
    constexpr int SROWS = ROWS + 2 * HALO;
    constexpr int F     = ROWS;
    constexpr int WPR   = 4 / ROWS;
    constexpr int CP    = (CIN > 64) ? 2 : 1;   // ci phases
    constexpr int CC    = CIN / CP;             // channels per phase
    constexpr int KBP   = KS * KS * CC / 32;    // k-steps per phase

    __shared__ ush sIn[SROWS * XW * CC];

    const int tid = threadIdx.x;
    const int b   = blockIdx.z / COB;
    const int co0 = (blockIdx.z % COB) * 64;
    const int y0  = blockIdx.y * ROWS;
    const int x0  = blockIdx.x * 64;

    const int lane = tid & 63, wid = tid >> 6;
    const int r   = wid / WPR;
    const int fb  = (wid % WPR) * F;
    const int l15 = lane & 15, lq = lane >> 4;

    f32x4 acc[4][F] = {};
    const ush* wp = wt + (size_t)(co0 + l15) * K + lq * 8;

#pragma unroll 1
    for (int ph = 0; ph < CP; ++ph) {
        if (ph) __syncthreads();
        constexpr int CHUNKS = SROWS * XW * CC / 8;
        for (int i = tid; i < CHUNKS; i += 256) {
            int ci8 = i % (CC / 8);
            int r2  = i / (CC / 8);
            int xi  = r2 % XW;
            int row = r2 / XW;
            int gy = y0 + row - HALO;
            int gx = x0 + xi - HALO;
            i32x4 v = {0, 0, 0, 0};
            if ((unsigned)gy < (unsigned)H && (unsigned)gx < (unsigned)W)
                v = ntld4(in + (((size_t)b * H + gy) * W + gx) * CIN + ph * CC + ci8 * 8);
            int bo = ((row * XW + xi) * CC + ci8 * 8) * 2;
            *(i32x4*)((char*)sIn + (bo ^ ((xi & 7) << 4))) = v;
        }
        __syncthreads();

#pragma unroll
        for (int kb = 0; kb < KBP; ++kb) {
            const int k0p  = kb * 32;
            const int cip0 = k0p % CC;
            const int kxy  = k0p / CC;
            const int kx = kxy % KS, ky = kxy / KS;
            const int kg = kxy * CIN + ph * CC + cip0;
            bf16x8 a[4];
#pragma unroll
            for (int m = 0; m < 4; ++m)
                a[m] = *(const bf16x8*)(wp + (size_t)m * 16 * K + kg);
#pragma unroll
            for (int n = 0; n < F; ++n) {
                const int xi = (fb + n) * 16 + l15 + kx;
                const int bo = (((r + ky) * XW + xi) * CC + cip0 + lq * 8) * 2;
                bf16x8 bv = *(const bf16x8*)((const char*)sIn + (bo ^ ((xi & 7) << 4)));
#pragma unroll
                for (int m = 0; m < 4; ++m)
                    acc[m][n] = __builtin_amdgcn_mfma_f32_16x16x32_bf16(a[m], bv, acc[m][n], 0, 0, 0);
            }
        }
    }

    const int y = y0 + r;
#pragma unroll
    for (int m = 0; m < 4; ++m) {
        const int com = co0 + m * 16 + lq * 4;
        float4 bvv = *(const float4*)(bias + com);
#pragma unroll
        for (int n = 0; n < F; ++n) {
            const int px = x0 + (fb + n) * 16 + l15;
            size_t oaddr = (((size_t)b * H + y) * W + px) * COUT + com;
            float v0 = acc[m][n][0] + bvv.x;
            float v1 = acc[m][n][1] + bvv.y;
            float v2 = acc[m][n][2] + bvv.z;
            float v3 = acc[m][n][3] + bvv.w;
            if constexpr (ADD) {
                s16x4 rv = __builtin_nontemporal_load((const s16x4*)(res + oaddr));
                v0 += bf2f((ush)rv[0]); v1 += bf2f((ush)rv[1]);
                v2 += bf2f((ush)rv[2]); v3 += bf2f((ush)rv[3]);
            }
            if constexpr (RELU) {
                v0 = fmaxf(v0, 0.f); v1 = fmaxf(v1, 0.f);
                v2 = fmaxf(v2, 0.f); v3 = fmaxf(v3, 0.f);
            }
            s16x4 o;
            o[0] = (short)f2bf(v0); o[1] = (short)f2bf(v1);
            o[2] = (short)f2bf(v2); o[3] = (short)f2bf(v3);
            __builtin_nontemporal_store(o, (s16x4*)(out + oaddr));
        }
    }
}

// ============ MFMA conv 3x3 stride 2 (128->128), out z NCHW fp32 ===========
// Split-CIN two-phase staging (25.3 KB LDS/phase). NT staging loads.
__global__ __launch_bounds__(256) void mconv_s2_z(
    const ush* __restrict__ in, const ush* __restrict__ wt,
    const float* __restrict__ bias, float* __restrict__ zout, int Hi, int Wi)
{
    constexpr int CIN = 128, COUT = 128, K = 1152, XW = 66, CC = 64;
    __shared__ ush sIn[3 * XW * CC];
    const int Ho = Hi >> 1, Wo = Wi >> 1;
    const int tid = threadIdx.x;
    const int b = blockIdx.z >> 1, co0 = (blockIdx.z & 1) * 64;
    const int yo = blockIdx.y, xo0 = blockIdx.x * 32;

    const int lane = tid & 63, wid = tid >> 6;
    const int wm = wid >> 1, wn = wid & 1;
    const int l15 = lane & 15, lq = lane >> 4;

    f32x4 acc[2] = {};
    const ush* wp  = wt + (size_t)(co0 + wm * 32 + l15) * K + lq * 8;
    const ush* wp2 = wp + 16 * K;
    const int pxl = wn * 16 + l15;

#pragma unroll 1
    for (int ph = 0; ph < 2; ++ph) {
        if (ph) __syncthreads();
        for (int i = tid; i < 3 * XW * CC / 8; i += 256) {
            int ci8 = i & 7;
            int r2  = i >> 3;
            int xi  = r2 % XW;
            int row = r2 / XW;
            int gy = 2 * yo + row - 1, gx = 2 * xo0 + xi - 1;
            i32x4 v = {0, 0, 0, 0};
            if ((unsigned)gy < (unsigned)Hi && (unsigned)gx < (unsigned)Wi)
                v = ntld4(in + (((size_t)b * Hi + gy) * Wi + gx) * CIN + ph * CC + ci8 * 8);
            int bo = ((row * XW + xi) * CC + ci8 * 8) * 2;
            *(i32x4*)((char*)sIn + (bo ^ ((xi & 7) << 4))) = v;
        }
        __syncthreads();

#pragma unroll
        for (int kb = 0; kb < 18; ++kb) {
            const int k0p  = kb * 32;
            const int cip0 = k0p % CC;
            const int kxy  = k0p / CC;
            const int kx = kxy % 3, ky = kxy / 3;
            const int kg = kxy * CIN + ph * CC + cip0;
            bf16x8 a0 = *(const bf16x8*)(wp  + kg);
            bf16x8 a1 = *(const bf16x8*)(wp2 + kg);
            const int xl = 2 * pxl + kx;
            const int bo = ((ky * XW + xl) * CC + cip0 + lq * 8) * 2;
            bf16x8 bfr = *(const bf16x8*)((const char*)sIn + (bo ^ ((xl & 7) << 4)));
            acc[0] = __builtin_amdgcn_mfma_f32_16x16x32_bf16(a0, bfr, acc[0], 0, 0, 0);
            acc[1] = __builtin_amdgcn_mfma_f32_16x16x32_bf16(a1, bfr, acc[1], 0, 0, 0);
        }
    }

    const int px = xo0 + pxl;
#pragma unroll
    for (int m = 0; m < 2; ++m) {
        const int com = co0 + wm * 32 + m * 16 + lq * 4;
        float4 bv = *(const float4*)(bias + com);
#pragma unroll
        for (int r = 0; r < 4; ++r) {
            float v = acc[m][r] + ((const float*)&bv)[r];
            v = fmaxf(v, 0.f);
            zout[(((size_t)b * COUT + com + r) * Ho + yo) * Wo + px] = v;
        }
    }
}

// ============ final conv 64->3, NHWC bf16 in -> NCHW f32 d_out =============
__global__ __launch_bounds__(256) void mconv_out(
    const ush* __restrict__ in, const ush* __restrict__ wt,
    const float* __restrict__ bias, float* __restrict__ outv, int H, int W)
{
    constexpr int K = 576, K32 = 18, XW = 66, SROWS = 6;
    __shared__ ush sIn[SROWS * XW * 64];
    const int tid = threadIdx.x;
    const int b = blockIdx.z, y0 = blockIdx.y * 4, x0 = blockIdx.x * 64;

    for (int i = tid; i < SROWS * XW * 64 / 8; i += 256) {
        int ci8 = i & 7;
        int r2  = i >> 3;
        int xi  = r2 % XW;
        int row = r2 / XW;
        int gy = y0 + row - 1, gx = x0 + xi - 1;
        i32x4 v = {0, 0, 0, 0};
        if ((unsigned)gy < (unsigned)H && (unsigned)gx < (unsigned)W)
            v = ntld4(in + (((size_t)b * H + gy) * W + gx) * 64 + ci8 * 8);
        int bo = ((row * XW + xi) * 64 + ci8 * 8) * 2;
        *(i32x4*)((char*)sIn + (bo ^ ((xi & 7) << 4))) = v;
    }
    __syncthreads();

    const int lane = tid & 63, wid = tid >> 6;
    const int l15 = lane & 15, lq = lane >> 4;
    const int r = wid;

    f32x4 acc[4] = {};
    const ush* wp = wt + (size_t)l15 * K + lq * 8;

#pragma unroll
    for (int kb = 0; kb < K32; ++kb) {
        const int k0 = kb * 32;
        const int ci0 = k0 % 64;
        const int kxy = k0 / 64;
        const int kx = kxy % 3, ky = kxy / 3;
        bf16x8 a0 = *(const bf16x8*)(wp + k0);
#pragma unroll
        for (int n = 0; n < 4; ++n) {
            const int xi = n * 16 + l15 + kx;
            const int bo = (((r + ky) * XW + xi) * 64 + ci0 + lq * 8) * 2;
            bf16x8 bfr = *(const bf16x8*)((const char*)sIn + (bo ^ ((xi & 7) << 4)));
            acc[n] = __builtin_amdgcn_mfma_f32_16x16x32_bf16(a0, bfr, acc[n], 0, 0, 0);
        }
    }

    const int y = y0 + r;
    if (lq == 0) {
#pragma unroll
        for (int n = 0; n < 4; ++n) {
            const int px = x0 + n * 16 + l15;
#pragma unroll
            for (int ch = 0; ch < 3; ++ch)
                __builtin_nontemporal_store(acc[n][ch] + bias[ch],
                    outv + (((size_t)b * 3 + ch) * H + y) * W + px);
        }
    }
}

// ============== q transpose: NCHW bf16 -> NHWC bf16 (C=H=W=128) ============
__global__ __launch_bounds__(256) void transpose_q(
    const ush* __restrict__ qc, ush* __restrict__ qh)
{
    __shared__ ush sT[128][136];
    const int tid = threadIdx.x;
    const int b = blockIdx.x >> 7, h = blockIdx.x & 127;

    for (int i = tid; i < 2048; i += 256) {
        int c = i >> 4, w8 = i & 15;
        int4 v = *(const int4*)(qc + (((size_t)b * 128 + c) * 128 + h) * 128 + w8 * 8);
        const ush* pv = (const ush*)&v;
#pragma unroll
        for (int j = 0; j < 8; ++j) sT[w8 * 8 + j][c] = pv[j];
    }
    __syncthreads();
    for (int i = tid; i < 2048; i += 256) {
        int w = i >> 4, c8 = i & 15;
        int4 v;
        ush* pv = (ush*)&v;
#pragma unroll
        for (int j = 0; j < 8; ++j) pv[j] = sT[w][c8 * 8 + j];
        *(int4*)(qh + (((size_t)b * 128 + h) * 128 + w) * 128 + c8 * 8) = v;
    }
}

// ================= nearest 2x upsample, NHWC bf16 (C=128) ==================
__global__ void upsample2x_nhwc(const ush* __restrict__ in, ush* __restrict__ out)
{
    long idx = (long)blockIdx.x * 256 + threadIdx.x;
    int c8 = (int)(idx & 15);
    int xx = (int)((idx >> 4) & 255);
    int yy = (int)((idx >> 12) & 255);
    int b  = (int)(idx >> 20);
    int4 v = *(const int4*)(in + (((size_t)b * 128 + (yy >> 1)) * 128 + (xx >> 1)) * 128 + c8 * 8);
    *(int4*)(out + (((size_t)b * 256 + yy) * 256 + xx) * 128 + c8 * 8) = v;
}

// ========================= codebook c^2 ====================================
__global__ void cb_transpose(const float* __restrict__ cb, float* __restrict__ cbT)
{
    int idx = blockIdx.x * 256 + threadIdx.x;
    if (idx < 1024 * 128) {
        int k = idx >> 7, e = idx & 127;
        cbT[e * 1024 + k] = cb[idx];
    }
}

__global__ void cb_c2(const float* __restrict__ cbT, float* __restrict__ c2)
{
    int k = blockIdx.x * 256 + threadIdx.x;
    if (k < 1024) {
        float s = 0.f;
        for (int e = 0; e < 128; ++e) {
            float v = cbT[e * 1024 + k];
            s = fmaf(v, v, s);
        }
        c2[k] = s;
    }
}

// ===================== MFMA quantizer ======================================
__global__ __launch_bounds__(256) void vq_mfma(
    const float* __restrict__ z, const float* __restrict__ cb,
    const char* __restrict__ cbImg, const float* __restrict__ c2,
    ush* __restrict__ q, float* __restrict__ partials)
{
    __shared__ ush   sB[32768];        // 64 KB codebook chunk (hi|lo)
    __shared__ float sC2[1024];
    __shared__ float sZ2p[128][2];
    __shared__ float sZ2[128];
    __shared__ int   sIdx[128];
    __shared__ float sRed[4];

    const int tid = threadIdx.x;
    const int wid = tid >> 6, lane = tid & 63;
    const int l15 = lane & 15, lq = lane >> 4;
    const size_t row0 = (size_t)blockIdx.x * 128;

    for (int i = tid; i < 1024; i += 256) sC2[i] = c2[i];

    {
        int row = tid >> 1, half = tid & 1;
        const float* zp = z + (row0 + row) * 128 + half * 64;
        float s = 0.f;
        for (int j = 0; j < 16; ++j) {
            float4 v = *(const float4*)(zp + j * 4);
            s = fmaf(v.x, v.x, s); s = fmaf(v.y, v.y, s);
            s = fmaf(v.z, v.z, s); s = fmaf(v.w, v.w, s);
        }
        sZ2p[row][half] = s;
    }
    __syncthreads();
    if (tid < 128) sZ2[tid] = sZ2p[tid][0] + sZ2p[tid][1];

    bf16x8 ahi[2][4], alo[2][4];
#pragma unroll
    for (int rt = 0; rt < 2; ++rt) {
#pragma unroll
        for (int ks = 0; ks < 4; ++ks) {
            const float* zp = z + (row0 + wid * 32 + rt * 16 + l15) * 128 + ks * 32 + lq * 8;
            float4 v0 = *(const float4*)zp;
            float4 v1 = *(const float4*)(zp + 4);
            float f[8] = {v0.x, v0.y, v0.z, v0.w, v1.x, v1.y, v1.z, v1.w};
            bf16x8 h, l;
#pragma unroll
            for (int j = 0; j < 8; ++j) {
                ush hb = f2bf(f[j]);
                h[j] = (short)hb;
                l[j] = (short)f2bf(f[j] - bf2f(hb));
            }
            ahi[rt][ks] = h; alo[rt][ks] = l;
        }
    }

    u64 bk[2][4];
#pragma unroll
    for (int rt = 0; rt < 2; ++rt)
#pragma unroll
        for (int rg = 0; rg < 4; ++rg) bk[rt][rg] = ~0ull;

#pragma unroll 1
    for (int p = 0; p < 8; ++p) {
        __syncthreads();
        {
            const int4* gsrc = (const int4*)(cbImg + (size_t)p * 65536);
            int4* ldst = (int4*)sB;
#pragma unroll
            for (int it = 0; it < 16; ++it)
                ldst[it * 256 + tid] = gsrc[it * 256 + tid];
        }
        __syncthreads();

        f32x4 acc[2][8] = {};
#pragma unroll
        for (int ks = 0; ks < 4; ++ks) {
#pragma unroll
            for (int ct = 0; ct < 8; ++ct) {
                int cidx = ct * 16 + l15;
                int boff = ((cidx * 128 + ks * 32 + lq * 8) * 2) ^ ((cidx & 7) << 4);
                bf16x8 bh = *(const bf16x8*)((const char*)sB + boff);
                bf16x8 bl = *(const bf16x8*)((const char*)sB + boff + 32768);
#pragma unroll
                for (int rt = 0; rt < 2; ++rt) {
                    acc[rt][ct] = __builtin_amdgcn_mfma_f32_16x16x32_bf16(ahi[rt][ks], bh, acc[rt][ct], 0, 0, 0);
                    acc[rt][ct] = __builtin_amdgcn_mfma_f32_16x16x32_bf16(alo[rt][ks], bh, acc[rt][ct], 0, 0, 0);
                    acc[rt][ct] = __builtin_amdgcn_mfma_f32_16x16x32_bf16(ahi[rt][ks], bl, acc[rt][ct], 0, 0, 0);
                }
            }
        }
#pragma unroll
        for (int rt = 0; rt < 2; ++rt) {
#pragma unroll
            for (int ct = 0; ct < 8; ++ct) {
                int code = p * 128 + ct * 16 + l15;
                float cc = sC2[code];
#pragma unroll
                for (int rg = 0; rg < 4; ++rg) {
                    float z2 = sZ2[wid * 32 + rt * 16 + lq * 4 + rg];
                    float d = (z2 - 2.0f * acc[rt][ct][rg]) + cc;
                    d = fmaxf(d, 0.f);
                    u64 key = ((u64)__float_as_uint(d) << 32) | (unsigned)code;
                    if (key < bk[rt][rg]) bk[rt][rg] = key;
                }
            }
        }
    }

#pragma unroll
    for (int rt = 0; rt < 2; ++rt) {
#pragma unroll
        for (int rg = 0; rg < 4; ++rg) {
            u64 k = bk[rt][rg];
#pragma unroll
            for (int m = 1; m < 16; m <<= 1) {
                u64 o = __shfl_xor(k, m, 64);
                if (o < k) k = o;
            }
            if (l15 == 0)
                sIdx[wid * 32 + rt * 16 + lq * 4 + rg] = (int)(k & 0xffffffffull);
        }
    }
    __syncthreads();

    float lsse = 0.f;
    {
        int row = tid >> 1, half = tid & 1;
        int code = sIdx[row];
        const float* cbrow = cb + (size_t)code * 128 + half * 64;
        const float* zrow  = z + (row0 + row) * 128 + half * 64;
        ush* qrow = q + (row0 + row) * 128 + half * 64;
        for (int j = 0; j < 16; ++j) {
            float4 cv = *(const float4*)(cbrow + j * 4);
            float4 zv = *(const float4*)(zrow + j * 4);
            float d0 = cv.x - zv.x, d1 = cv.y - zv.y;
            float d2 = cv.z - zv.z, d3 = cv.w - zv.w;
            lsse = fmaf(d0, d0, lsse); lsse = fmaf(d1, d1, lsse);
            lsse = fmaf(d2, d2, lsse); lsse = fmaf(d3, d3, lsse);
            ushort4 o;
            o.x = f2bf(zv.x + d0); o.y = f2bf(zv.y + d1);
            o.z = f2bf(zv.z + d2); o.w = f2bf(zv.w + d3);
            *(ushort4*)(qrow + j * 4) = o;
        }
    }
#pragma unroll
    for (int off = 32; off > 0; off >>= 1) lsse += __shfl_down(lsse, off, 64);
    if (lane == 0) sRed[wid] = lsse;
    __syncthreads();
    if (tid == 0) partials[blockIdx.x] = (sRed[0] + sRed[1]) + (sRed[2] + sRed[3]);
}

// ============================ loss finalize ================================
__global__ __launch_bounds__(256) void loss_finish(
    const float* __restrict__ partials, float* __restrict__ outLoss)
{
    __shared__ float sR[256];
    float s = 0.f;
    for (int i = threadIdx.x; i < 1024; i += 256) s += partials[i];
    sR[threadIdx.x] = s;
    __syncthreads();
    for (int st = 128; st > 0; st >>= 1) {
        if (threadIdx.x < st) sR[threadIdx.x] += sR[threadIdx.x + st];
        __syncthreads();
    }
    if (threadIdx.x == 0) {
        float m = sR[0] / 16777216.0f;
        outLoss[0] = m + 0.25f * m;
    }
}

// ============================= launcher ====================================
extern "C" void kernel_launch(void* const* d_in, const int* in_sizes, int n_in,
                              void* d_out, int out_size, void* d_ws, size_t ws_size,
                              hipStream_t stream)
{
    const float* x        = (const float*)d_in[0];
    const float* enc_in_w = (const float*)d_in[1];
    const float* enc_in_b = (const float*)d_in[2];
    const float* rb0_w1   = (const float*)d_in[3];
    const float* rb0_b1   = (const float*)d_in[4];
    const float* rb0_w2   = (const float*)d_in[5];
    const float* rb0_b2   = (const float*)d_in[6];
    const float* rb1_w1   = (const float*)d_in[7];
    const float* rb1_b1   = (const float*)d_in[8];
    const float* rb1_w2   = (const float*)d_in[9];
    const float* rb1_b2   = (const float*)d_in[10];
    const float* rb1_ws   = (const float*)d_in[11];
    const float* rb1_bs   = (const float*)d_in[12];
    const float* down_w   = (const float*)d_in[13];
    const float* down_b   = (const float*)d_in[14];
    const float* codebook = (const float*)d_in[15];
    const float* d1_w1    = (const float*)d_in[16];
    const float* d1_b1    = (const float*)d_in[17];
    const float* d1_w2    = (const float*)d_in[18];
    const float* d1_b2    = (const float*)d_in[19];
    const float* up_w     = (const float*)d_in[20];
    const float* up_b     = (const float*)d_in[21];
    const float* d0_w1    = (const float*)d_in[22];
    const float* d0_b1    = (const float*)d_in[23];
    const float* d0_w2    = (const float*)d_in[24];
    const float* d0_b2    = (const float*)d_in[25];
    const float* out_w    = (const float*)d_in[26];
    const float* out_b    = (const float*)d_in[27];
    (void)in_sizes; (void)n_in; (void)out_size;

    const size_t MB = 1ull << 20;
    char* ws = (char*)d_ws;
    float* partials = (float*)ws;                  // 1024 f32
    float* c2v      = (float*)(ws + 32 * 1024);    // 1024 f32
    float* cbT      = (float*)(ws + 64 * 1024);    // 128x1024 f32 (512 KB)
    char*  cbImg    = ws + 1 * MB;                 // 512 KB split hi/lo image
    ush*   wreg     = (ush*)(ws + 1 * MB + 512 * 1024);

    ush* w_rb0_1 = wreg + 0;
    ush* w_rb0_2 = wreg + 36864;
    ush* w_rb1_1 = wreg + 73728;
    ush* w_rb1_2 = wreg + 147456;
    ush* w_rb1_s = wreg + 294912;
    ush* w_down  = wreg + 303104;
    ush* w_d1_1  = wreg + 450560;
    ush* w_d1_2  = wreg + 598016;
    ush* w_up    = wreg + 745472;
    ush* w_d0_1  = wreg + 819200;
    ush* w_d0_2  = wreg + 856064;
    ush* w_out   = wreg + 892928;

    char* base = ws + 4 * MB;

    int cbn = 8;
    while (cbn > 1 && 4 * MB + (size_t)cbn * 56 * MB > ws_size) cbn >>= 1;

    auto prep = [&](const float* src, ush* dst, int O, int I, int KSp, int Opad) {
        int tot = Opad * KSp * KSp * I;
        prep_w<<<dim3((tot + 255) / 256), 256, 0, stream>>>(src, dst, O, I, KSp, Opad);
    };
    prep(rb0_w1, w_rb0_1, 64, 64, 3, 64);
    prep(rb0_w2, w_rb0_2, 64, 64, 3, 64);
    prep(rb1_w1, w_rb1_1, 128, 64, 3, 128);
    prep(rb1_w2, w_rb1_2, 128, 128, 3, 128);
    prep(rb1_ws, w_rb1_s, 128, 64, 1, 128);
    prep(down_w, w_down, 128, 128, 3, 128);
    prep(d1_w1, w_d1_1, 128, 128, 3, 128);
    prep(d1_w2, w_d1_2, 128, 128, 3, 128);
    prep(up_w, w_up, 64, 128, 3, 64);
    prep(d0_w1, w_d0_1, 64, 64, 3, 64);
    prep(d0_w2, w_d0_2, 64, 64, 3, 64);
    prep(out_w, w_out, 3, 64, 3, 16);

    cb_transpose<<<dim3(512), 256, 0, stream>>>(codebook, cbT);
    cb_c2<<<dim3(4), 256, 0, stream>>>(cbT, c2v);
    prep_cb_split<<<dim3(512), 256, 0, stream>>>(codebook, cbImg);

    for (int e0 = 0; e0 < 8; e0 += cbn) {
        const float* xc   = x + (size_t)e0 * 3 * 65536;
        float*       outc = (float*)d_out + (size_t)e0 * 3 * 65536;

        ush*   h0 = (ush*)(base + (size_t)cbn * 0 * MB);
        ush*   t  = (ush*)(base + (size_t)cbn * 8 * MB);
        ush*   r0 = (ush*)(base + (size_t)cbn * 16 * MB);
        ush*   t1 = (ush*)(base + (size_t)cbn * 24 * MB);
        ush*   r1 = (ush*)(base + (size_t)cbn * 40 * MB);
        float* z  = (float*)(base + (size_t)cbn * 0 * MB);
        ush*   qc = (ush*)(base + (size_t)cbn * 8 * MB);
        ush*   qh = (ush*)(base + (size_t)cbn * 12 * MB);
        ush*   dt = (ush*)(base + (size_t)cbn * 16 * MB);
        ush*   dr = (ush*)(base + (size_t)cbn * 20 * MB);
        ush*   up = (ush*)(base + (size_t)cbn * 24 * MB);
        ush*   u  = (ush*)(base + (size_t)cbn * 40 * MB);
        ush*   t2 = (ush*)(base + (size_t)cbn * 0 * MB);
        ush*   r2 = (ush*)(base + (size_t)cbn * 8 * MB);

        // ---------------- encoder ----------------
        enc_in_k<<<dim3(256, cbn), 256, 0, stream>>>(xc, enc_in_w, enc_in_b, h0);
        mconv<64, 64, 3, 4, true, false><<<dim3(4, 64, cbn), 256, 0, stream>>>(
            h0, w_rb0_1, rb0_b1, nullptr, t, 256, 256);
        mconv<64, 64, 3, 4, true, true><<<dim3(4, 64, cbn), 256, 0, stream>>>(
            t, w_rb0_2, rb0_b2, h0, r0, 256, 256);
        mconv<64, 128, 3, 4, true, false><<<dim3(4, 64, 2 * cbn), 256, 0, stream>>>(
            r0, w_rb1_1, rb1_b1, nullptr, t1, 256, 256);
        mconv<64, 128, 1, 4, false, false><<<dim3(4, 64, 2 * cbn), 256, 0, stream>>>(
            r0, w_rb1_s, rb1_bs, nullptr, r1, 256, 256);
        mconv<128, 128, 3, 2, true, true><<<dim3(4, 128, 2 * cbn), 256, 0, stream>>>(
            t1, w_rb1_2, rb1_b2, r1, r1, 256, 256);
        mconv_s2_z<<<dim3(4, 128, 2 * cbn), 256, 0, stream>>>(
            r1, w_down, down_b, z, 256, 256);

        // ---------------- quantizer ----------------
        vq_mfma<<<dim3(cbn * 128), 256, 0, stream>>>(
            z, codebook, cbImg, c2v, qc, partials + (size_t)e0 * 128);
        transpose_q<<<dim3(cbn * 128), 256, 0, stream>>>(qc, qh);

        // ---------------- decoder ----------------
        mconv<128, 128, 3, 2, true, false><<<dim3(2, 64, 2 * cbn), 256, 0, stream>>>(
            qh, w_d1_1, d1_b1, nullptr, dt, 128, 128);
        mconv<128, 128, 3, 2, true, true><<<dim3(2, 64, 2 * cbn), 256, 0, stream>>>(
            dt, w_d1_2, d1_b2, qh, dr, 128, 128);
        upsample2x_nhwc<<<dim3(cbn * 4096), 256, 0, stream>>>(dr, up);
        mconv<128, 64, 3, 2, true, false><<<dim3(4, 128, cbn), 256, 0, stream>>>(
            up, w_up, up_b, nullptr, u, 256, 256);
        mconv<64, 64, 3, 4, true, false><<<dim3(4, 64, cbn), 256, 0, stream>>>(
            u, w_d0_1, d0_b1, nullptr, t2, 256, 256);
        mconv<64, 64, 3, 4, true, true><<<dim3(4, 64, cbn), 256, 0, stream>>>(
            t2, w_d0_2, d0_b2, u, r2, 256, 256);
        mconv_out<<<dim3(4, 64, cbn), 256, 0, stream>>>(
            r2, w_out, out_b, outc, 256, 256);
    }

    // ---------------- loss ----------------
    loss_finish<<<dim3(1), 256, 0, stream>>>(partials, (float*)d_out + 1572864);
}

// Round 7
// 1882.740 us; speedup vs baseline: 1.7707x; 1.7707x over previous
//
#include <hip/hip_runtime.h>

// ---------------------------------------------------------------------------
// VQ-VAE forward: bf16 MFMA implicit-GEMM convs (NHWC) + split-bf16 MFMA VQ.
// R7: double-buffered LDS weight tiles (kxy-major repack) -> no global loads
// in the MFMA K-loop; NT only on input staging; plain stores (NT-store revert).
// ---------------------------------------------------------------------------

typedef float    f32x4  __attribute__((ext_vector_type(4)));
typedef short    bf16x8 __attribute__((ext_vector_type(8)));
typedef int      i32x4  __attribute__((ext_vector_type(4)));
typedef unsigned short ush;
typedef unsigned long long u64;

__device__ __forceinline__ ush f2bf(float f) {
    unsigned u = __float_as_uint(f);
    u += 0x7fff + ((u >> 16) & 1);          // round-to-nearest-even
    return (ush)(u >> 16);
}
__device__ __forceinline__ float bf2f(ush h) {
    return __uint_as_float(((unsigned)h) << 16);
}
__device__ __forceinline__ i32x4 ntld4(const void* p) {
    return __builtin_nontemporal_load((const i32x4*)p);
}

// ========== weight repack OIHW f32 -> kxy-major bf16 [kxy][o][i] ===========
__global__ void prep_w(const float* __restrict__ src, ush* __restrict__ dst,
                       int O, int I, int KS, int Opad)
{
    int idx = blockIdx.x * 256 + threadIdx.x;
    if (idx >= Opad * KS * KS * I) return;
    int ci  = idx % I;
    int rem = idx / I;
    int o   = rem % Opad;
    int kxy = rem / Opad;
    int kx = kxy % KS, ky = kxy / KS;
    float v = 0.f;
    if (o < O) v = src[((size_t)(o * I + ci) * KS + ky) * KS + kx];
    dst[((size_t)kxy * Opad + o) * I + ci] = f2bf(v);
}

// ============ codebook split hi/lo, pre-swizzled LDS image =================
__global__ void prep_cb_split(const float* __restrict__ cb, char* __restrict__ img)
{
    int idx = blockIdx.x * 256 + threadIdx.x;   // 1024*128
    if (idx >= 1024 * 128) return;
    int k = idx >> 7, e = idx & 127;
    int chunk = k >> 7, cidx = k & 127;
    float c = cb[idx];
    ush hi = f2bf(c);
    ush lo = f2bf(c - bf2f(hi));
    int boff = (((cidx * 128) + e) * 2) ^ ((cidx & 7) << 4);
    char* base = img + (size_t)chunk * 65536;
    *(ush*)(base + boff) = hi;
    *(ush*)(base + boff + 32768) = lo;
}

// ===================== enc_in: 3->64, NCHW f32 in -> NHWC bf16 out =========
__global__ __launch_bounds__(256) void enc_in_k(
    const float* __restrict__ x, const float* __restrict__ w,
    const float* __restrict__ bias, ush* __restrict__ out)
{
    __shared__ float sX[3][3][260];
    __shared__ float sW[27][64];
    __shared__ float sB[64];
    const int tid = threadIdx.x;
    const int y = blockIdx.x, b = blockIdx.y;

    for (int i = tid; i < 3 * 3 * 258; i += 256) {
        int xi = i % 258;
        int r  = (i / 258) % 3;
        int c  = i / 774;
        int gy = y + r - 1, gx = xi - 1;
        float v = 0.f;
        if ((unsigned)gy < 256u && (unsigned)gx < 256u)
            v = x[(((size_t)b * 3 + c) * 256 + gy) * 256 + gx];
        sX[c][r][xi] = v;
    }
    for (int i = tid; i < 1728; i += 256) {
        int co = i & 63, k = i >> 6;
        int c = k % 3, kxy = k / 3;
        int kx = kxy % 3, ky = kxy / 3;
        sW[k][co] = w[co * 27 + c * 9 + ky * 3 + kx];
    }
    if (tid < 64) sB[tid] = bias[tid];
    __syncthreads();

    float acc[64];
#pragma unroll
    for (int c = 0; c < 64; ++c) acc[c] = 0.f;
    const int px = tid;
#pragma unroll
    for (int k = 0; k < 27; ++k) {
        const int c = k % 3, kxy = k / 3;
        const int kx = kxy % 3, ky = kxy / 3;
        float iv = sX[c][ky][px + kx];
#pragma unroll
        for (int co = 0; co < 64; ++co) acc[co] = fmaf(iv, sW[k][co], acc[co]);
    }
    ush* op = out + (((size_t)b * 256 + y) * 256 + px) * 64;
#pragma unroll
    for (int c8 = 0; c8 < 8; ++c8) {
        ush tmp[8];
#pragma unroll
        for (int j = 0; j < 8; ++j) tmp[j] = f2bf(acc[c8 * 8 + j] + sB[c8 * 8 + j]);
        *(int4*)(op + c8 * 8) = *(const int4*)tmp;
    }
}

// ===================== MFMA conv, stride 1, NHWC bf16 ======================
// Block: 64 cout x 64 px x ROWS rows, 4 waves. Per kxy: 8KB weight slab
// double-buffered in LDS (issue-early/write-late); K-loop is LDS-only.
template<int CIN, int COUT, int KS, int ROWS, bool RELU, bool ADD>
__global__ __launch_bounds__(256) void mconv(
    const ush* __restrict__ in, const ush* __restrict__ wt,
    const float* __restrict__ bias, const ush* __restrict__ res,
    ush* __restrict__ out, int H, int W)
{
    constexpr int HALO  = KS / 2;
    constexpr int XW    = 64 + 2 * HALO;
    constexpr int COB   = COUT / 64;
    constexpr int SROWS = ROWS + 2 * HALO;
    constexpr int F     = ROWS;
    constexpr int WPR   = 4 / ROWS;
    constexpr int CP    = (CIN > 64) ? 2 : 1;
    constexpr int CC    = CIN / CP;
    constexpr int KK    = KS * KS;

    __shared__ ush sIn[SROWS * XW * CC];
    __shared__ ush sW[2][64 * CC];

    const int tid = threadIdx.x;
    const int b   = blockIdx.z / COB;
    const int co0 = (blockIdx.z % COB) * 64;
    const int y0  = blockIdx.y * ROWS;
    const int x0  = blockIdx.x * 64;

    const int lane = tid & 63, wid = tid >> 6;
    const int r   = wid / WPR;
    const int fb  = (wid % WPR) * F;
    const int l15 = lane & 15, lq = lane >> 4;

    // this thread's two weight chunks (512 x 16B per slab)
    const int co_a0 = tid >> 3,           ci8_a = tid & 7;
    const int co_b0 = (tid + 256) >> 3,   ci8_b = tid & 7;
    const int wdstA = ((co_a0 * CC + ci8_a * 8) * 2) ^ ((co_a0 & 7) << 4);
    const int wdstB = ((co_b0 * CC + ci8_b * 8) * 2) ^ ((co_b0 & 7) << 4);

    f32x4 acc[4][F] = {};

#pragma unroll 1
    for (int ph = 0; ph < CP; ++ph) {
        if (ph) __syncthreads();
        // ---- input stage (NT loads, XOR swizzle) ----
        constexpr int CHUNKS = SROWS * XW * CC / 8;
        for (int i = tid; i < CHUNKS; i += 256) {
            int ci8 = i % (CC / 8);
            int r2  = i / (CC / 8);
            int xi  = r2 % XW;
            int row = r2 / XW;
            int gy = y0 + row - HALO;
            int gx = x0 + xi - HALO;
            i32x4 v = {0, 0, 0, 0};
            if ((unsigned)gy < (unsigned)H && (unsigned)gx < (unsigned)W)
                v = ntld4(in + (((size_t)b * H + gy) * W + gx) * CIN + ph * CC + ci8 * 8);
            int bo = ((row * XW + xi) * CC + ci8 * 8) * 2;
            *(i32x4*)((char*)sIn + (bo ^ ((xi & 7) << 4))) = v;
        }
        // ---- weight prologue: kxy=0 -> buf0 ----
        {
            const ush* slab = wt + (size_t)co0 * CIN + ph * CC;
            i32x4 v0 = *(const i32x4*)(slab + (size_t)co_a0 * CIN + ci8_a * 8);
            i32x4 v1 = *(const i32x4*)(slab + (size_t)co_b0 * CIN + ci8_b * 8);
            *(i32x4*)((char*)sW[0] + wdstA) = v0;
            *(i32x4*)((char*)sW[0] + wdstB) = v1;
        }
        __syncthreads();

        int curb = 0;
#pragma unroll 1
        for (int kxy = 0; kxy < KK; ++kxy) {
            const int kx = kxy % KS, ky = kxy / KS;
            i32x4 w0, w1;
            const bool hn = (kxy + 1 < KK);
            if (hn) {
                const ush* slab = wt + ((size_t)(kxy + 1) * COUT + co0) * CIN + ph * CC;
                w0 = *(const i32x4*)(slab + (size_t)co_a0 * CIN + ci8_a * 8);
                w1 = *(const i32x4*)(slab + (size_t)co_b0 * CIN + ci8_b * 8);
            }
#pragma unroll
            for (int kb2 = 0; kb2 < CC / 32; ++kb2) {
                const int cip0 = kb2 * 32;
                bf16x8 a[4];
#pragma unroll
                for (int m = 0; m < 4; ++m) {
                    const int coa = m * 16 + l15;
                    a[m] = *(const bf16x8*)((const char*)sW[curb] +
                           (((coa * CC + cip0 + lq * 8) * 2) ^ ((coa & 7) << 4)));
                }
#pragma unroll
                for (int n = 0; n < F; ++n) {
                    const int xi = (fb + n) * 16 + l15 + kx;
                    const int bo = (((r + ky) * XW + xi) * CC + cip0 + lq * 8) * 2;
                    bf16x8 bv = *(const bf16x8*)((const char*)sIn + (bo ^ ((xi & 7) << 4)));
#pragma unroll
                    for (int m = 0; m < 4; ++m)
                        acc[m][n] = __builtin_amdgcn_mfma_f32_16x16x32_bf16(a[m], bv, acc[m][n], 0, 0, 0);
                }
            }
            if (hn) {
                *(i32x4*)((char*)sW[curb ^ 1] + wdstA) = w0;
                *(i32x4*)((char*)sW[curb ^ 1] + wdstB) = w1;
            }
            __syncthreads();
            curb ^= 1;
        }
    }

    const int y = y0 + r;
#pragma unroll
    for (int m = 0; m < 4; ++m) {
        const int com = co0 + m * 16 + lq * 4;
        float4 bvv = *(const float4*)(bias + com);
#pragma unroll
        for (int n = 0; n < F; ++n) {
            const int px = x0 + (fb + n) * 16 + l15;
            size_t oaddr = (((size_t)b * H + y) * W + px) * COUT + com;
            float v0 = acc[m][n][0] + bvv.x;
            float v1 = acc[m][n][1] + bvv.y;
            float v2 = acc[m][n][2] + bvv.z;
            float v3 = acc[m][n][3] + bvv.w;
            if constexpr (ADD) {
                ushort4 rv = *(const ushort4*)(res + oaddr);
                v0 += bf2f(rv.x); v1 += bf2f(rv.y);
                v2 += bf2f(rv.z); v3 += bf2f(rv.w);
            }
            if constexpr (RELU) {
                v0 = fmaxf(v0, 0.f); v1 = fmaxf(v1, 0.f);
                v2 = fmaxf(v2, 0.f); v3 = fmaxf(v3, 0.f);
            }
            ushort4 o;
            o.x = f2bf(v0); o.y = f2bf(v1); o.z = f2bf(v2); o.w = f2bf(v3);
            *(ushort4*)(out + oaddr) = o;
        }
    }
}

// ============ MFMA conv 3x3 stride 2 (128->128), out z NCHW fp32 ===========
__global__ __launch_bounds__(256) void mconv_s2_z(
    const ush* __restrict__ in, const ush* __restrict__ wt,
    const float* __restrict__ bias, float* __restrict__ zout, int Hi, int Wi)
{
    constexpr int CIN = 128, COUT = 128, XW = 66, CC = 64;
    __shared__ ush sIn[3 * XW * CC];
    __shared__ ush sW[2][64 * CC];
    const int Ho = Hi >> 1, Wo = Wi >> 1;
    const int tid = threadIdx.x;
    const int b = blockIdx.z >> 1, co0 = (blockIdx.z & 1) * 64;
    const int yo = blockIdx.y, xo0 = blockIdx.x * 32;

    const int lane = tid & 63, wid = tid >> 6;
    const int wm = wid >> 1, wn = wid & 1;
    const int l15 = lane & 15, lq = lane >> 4;
    const int pxl = wn * 16 + l15;

    const int co_a0 = tid >> 3,         ci8_a = tid & 7;
    const int co_b0 = (tid + 256) >> 3, ci8_b = tid & 7;
    const int wdstA = ((co_a0 * CC + ci8_a * 8) * 2) ^ ((co_a0 & 7) << 4);
    const int wdstB = ((co_b0 * CC + ci8_b * 8) * 2) ^ ((co_b0 & 7) << 4);

    f32x4 acc[2] = {};

#pragma unroll 1
    for (int ph = 0; ph < 2; ++ph) {
        if (ph) __syncthreads();
        for (int i = tid; i < 3 * XW * CC / 8; i += 256) {
            int ci8 = i & 7;
            int r2  = i >> 3;
            int xi  = r2 % XW;
            int row = r2 / XW;
            int gy = 2 * yo + row - 1, gx = 2 * xo0 + xi - 1;
            i32x4 v = {0, 0, 0, 0};
            if ((unsigned)gy < (unsigned)Hi && (unsigned)gx < (unsigned)Wi)
                v = ntld4(in + (((size_t)b * Hi + gy) * Wi + gx) * CIN + ph * CC + ci8 * 8);
            int bo = ((row * XW + xi) * CC + ci8 * 8) * 2;
            *(i32x4*)((char*)sIn + (bo ^ ((xi & 7) << 4))) = v;
        }
        {
            const ush* slab = wt + (size_t)co0 * CIN + ph * CC;
            i32x4 v0 = *(const i32x4*)(slab + (size_t)co_a0 * CIN + ci8_a * 8);
            i32x4 v1 = *(const i32x4*)(slab + (size_t)co_b0 * CIN + ci8_b * 8);
            *(i32x4*)((char*)sW[0] + wdstA) = v0;
            *(i32x4*)((char*)sW[0] + wdstB) = v1;
        }
        __syncthreads();

        int curb = 0;
#pragma unroll 1
        for (int kxy = 0; kxy < 9; ++kxy) {
            const int kx = kxy % 3, ky = kxy / 3;
            i32x4 w0, w1;
            const bool hn = (kxy + 1 < 9);
            if (hn) {
                const ush* slab = wt + ((size_t)(kxy + 1) * COUT + co0) * CIN + ph * CC;
                w0 = *(const i32x4*)(slab + (size_t)co_a0 * CIN + ci8_a * 8);
                w1 = *(const i32x4*)(slab + (size_t)co_b0 * CIN + ci8_b * 8);
            }
#pragma unroll
            for (int kb2 = 0; kb2 < 2; ++kb2) {
                const int cip0 = kb2 * 32;
                bf16x8 a[2];
#pragma unroll
                for (int m = 0; m < 2; ++m) {
                    const int coa = wm * 32 + m * 16 + l15;
                    a[m] = *(const bf16x8*)((const char*)sW[curb] +
                           (((coa * CC + cip0 + lq * 8) * 2) ^ ((coa & 7) << 4)));
                }
                const int xl = 2 * pxl + kx;
                const int bo = ((ky * XW + xl) * CC + cip0 + lq * 8) * 2;
                bf16x8 bfr = *(const bf16x8*)((const char*)sIn + (bo ^ ((xl & 7) << 4)));
                acc[0] = __builtin_amdgcn_mfma_f32_16x16x32_bf16(a[0], bfr, acc[0], 0, 0, 0);
                acc[1] = __builtin_amdgcn_mfma_f32_16x16x32_bf16(a[1], bfr, acc[1], 0, 0, 0);
            }
            if (hn) {
                *(i32x4*)((char*)sW[curb ^ 1] + wdstA) = w0;
                *(i32x4*)((char*)sW[curb ^ 1] + wdstB) = w1;
            }
            __syncthreads();
            curb ^= 1;
        }
    }

    const int px = xo0 + pxl;
#pragma unroll
    for (int m = 0; m < 2; ++m) {
        const int com = co0 + wm * 32 + m * 16 + lq * 4;
        float4 bv = *(const float4*)(bias + com);
#pragma unroll
        for (int r = 0; r < 4; ++r) {
            float v = acc[m][r] + ((const float*)&bv)[r];
            v = fmaxf(v, 0.f);
            zout[(((size_t)b * COUT + com + r) * Ho + yo) * Wo + px] = v;
        }
    }
}

// ============ final conv 64->3, NHWC bf16 in -> NCHW f32 d_out =============
__global__ __launch_bounds__(256) void mconv_out(
    const ush* __restrict__ in, const ush* __restrict__ wt,
    const float* __restrict__ bias, float* __restrict__ outv, int H, int W)
{
    constexpr int K32 = 18, XW = 66, SROWS = 6;
    __shared__ ush sIn[SROWS * XW * 64];
    const int tid = threadIdx.x;
    const int b = blockIdx.z, y0 = blockIdx.y * 4, x0 = blockIdx.x * 64;

    for (int i = tid; i < SROWS * XW * 64 / 8; i += 256) {
        int ci8 = i & 7;
        int r2  = i >> 3;
        int xi  = r2 % XW;
        int row = r2 / XW;
        int gy = y0 + row - 1, gx = x0 + xi - 1;
        i32x4 v = {0, 0, 0, 0};
        if ((unsigned)gy < (unsigned)H && (unsigned)gx < (unsigned)W)
            v = ntld4(in + (((size_t)b * H + gy) * W + gx) * 64 + ci8 * 8);
        int bo = ((row * XW + xi) * 64 + ci8 * 8) * 2;
        *(i32x4*)((char*)sIn + (bo ^ ((xi & 7) << 4))) = v;
    }
    __syncthreads();

    const int lane = tid & 63, wid = tid >> 6;
    const int l15 = lane & 15, lq = lane >> 4;
    const int r = wid;

    f32x4 acc[4] = {};

#pragma unroll
    for (int kb = 0; kb < K32; ++kb) {
        const int k0 = kb * 32;
        const int ci0 = k0 % 64;
        const int kxy = k0 / 64;
        const int kx = kxy % 3, ky = kxy / 3;
        // kxy-major layout: [kxy][16][64]
        bf16x8 a0 = *(const bf16x8*)(wt + ((size_t)kxy * 16 + l15) * 64 + ci0 + lq * 8);
#pragma unroll
        for (int n = 0; n < 4; ++n) {
            const int xi = n * 16 + l15 + kx;
            const int bo = (((r + ky) * XW + xi) * 64 + ci0 + lq * 8) * 2;
            bf16x8 bfr = *(const bf16x8*)((const char*)sIn + (bo ^ ((xi & 7) << 4)));
            acc[n] = __builtin_amdgcn_mfma_f32_16x16x32_bf16(a0, bfr, acc[n], 0, 0, 0);
        }
    }

    const int y = y0 + r;
    if (lq == 0) {
#pragma unroll
        for (int n = 0; n < 4; ++n) {
            const int px = x0 + n * 16 + l15;
#pragma unroll
            for (int ch = 0; ch < 3; ++ch)
                outv[(((size_t)b * 3 + ch) * H + y) * W + px] = acc[n][ch] + bias[ch];
        }
    }
}

// ============== q transpose: NCHW bf16 -> NHWC bf16 (C=H=W=128) ============
__global__ __launch_bounds__(256) void transpose_q(
    const ush* __restrict__ qc, ush* __restrict__ qh)
{
    __shared__ ush sT[128][136];
    const int tid = threadIdx.x;
    const int b = blockIdx.x >> 7, h = blockIdx.x & 127;

    for (int i = tid; i < 2048; i += 256) {
        int c = i >> 4, w8 = i & 15;
        int4 v = *(const int4*)(qc + (((size_t)b * 128 + c) * 128 + h) * 128 + w8 * 8);
        const ush* pv = (const ush*)&v;
#pragma unroll
        for (int j = 0; j < 8; ++j) sT[w8 * 8 + j][c] = pv[j];
    }
    __syncthreads();
    for (int i = tid; i < 2048; i += 256) {
        int w = i >> 4, c8 = i & 15;
        int4 v;
        ush* pv = (ush*)&v;
#pragma unroll
        for (int j = 0; j < 8; ++j) pv[j] = sT[w][c8 * 8 + j];
        *(int4*)(qh + (((size_t)b * 128 + h) * 128 + w) * 128 + c8 * 8) = v;
    }
}

// ================= nearest 2x upsample, NHWC bf16 (C=128) ==================
__global__ void upsample2x_nhwc(const ush* __restrict__ in, ush* __restrict__ out)
{
    long idx = (long)blockIdx.x * 256 + threadIdx.x;
    int c8 = (int)(idx & 15);
    int xx = (int)((idx >> 4) & 255);
    int yy = (int)((idx >> 12) & 255);
    int b  = (int)(idx >> 20);
    int4 v = *(const int4*)(in + (((size_t)b * 128 + (yy >> 1)) * 128 + (xx >> 1)) * 128 + c8 * 8);
    *(int4*)(out + (((size_t)b * 256 + yy) * 256 + xx) * 128 + c8 * 8) = v;
}

// ========================= codebook c^2 ====================================
__global__ void cb_transpose(const float* __restrict__ cb, float* __restrict__ cbT)
{
    int idx = blockIdx.x * 256 + threadIdx.x;
    if (idx < 1024 * 128) {
        int k = idx >> 7, e = idx & 127;
        cbT[e * 1024 + k] = cb[idx];
    }
}

__global__ void cb_c2(const float* __restrict__ cbT, float* __restrict__ c2)
{
    int k = blockIdx.x * 256 + threadIdx.x;
    if (k < 1024) {
        float s = 0.f;
        for (int e = 0; e < 128; ++e) {
            float v = cbT[e * 1024 + k];
            s = fmaf(v, v, s);
        }
        c2[k] = s;
    }
}

// ===================== MFMA quantizer ======================================
__global__ __launch_bounds__(256) void vq_mfma(
    const float* __restrict__ z, const float* __restrict__ cb,
    const char* __restrict__ cbImg, const float* __restrict__ c2,
    ush* __restrict__ q, float* __restrict__ partials)
{
    __shared__ ush   sB[32768];        // 64 KB codebook chunk (hi|lo)
    __shared__ float sC2[1024];
    __shared__ float sZ2p[128][2];
    __shared__ float sZ2[128];
    __shared__ int   sIdx[128];
    __shared__ float sRed[4];

    const int tid = threadIdx.x;
    const int wid = tid >> 6, lane = tid & 63;
    const int l15 = lane & 15, lq = lane >> 4;
    const size_t row0 = (size_t)blockIdx.x * 128;

    for (int i = tid; i < 1024; i += 256) sC2[i] = c2[i];

    {
        int row = tid >> 1, half = tid & 1;
        const float* zp = z + (row0 + row) * 128 + half * 64;
        float s = 0.f;
        for (int j = 0; j < 16; ++j) {
            float4 v = *(const float4*)(zp + j * 4);
            s = fmaf(v.x, v.x, s); s = fmaf(v.y, v.y, s);
            s = fmaf(v.z, v.z, s); s = fmaf(v.w, v.w, s);
        }
        sZ2p[row][half] = s;
    }
    __syncthreads();
    if (tid < 128) sZ2[tid] = sZ2p[tid][0] + sZ2p[tid][1];

    bf16x8 ahi[2][4], alo[2][4];
#pragma unroll
    for (int rt = 0; rt < 2; ++rt) {
#pragma unroll
        for (int ks = 0; ks < 4; ++ks) {
            const float* zp = z + (row0 + wid * 32 + rt * 16 + l15) * 128 + ks * 32 + lq * 8;
            float4 v0 = *(const float4*)zp;
            float4 v1 = *(const float4*)(zp + 4);
            float f[8] = {v0.x, v0.y, v0.z, v0.w, v1.x, v1.y, v1.z, v1.w};
            bf16x8 h, l;
#pragma unroll
            for (int j = 0; j < 8; ++j) {
                ush hb = f2bf(f[j]);
                h[j] = (short)hb;
                l[j] = (short)f2bf(f[j] - bf2f(hb));
            }
            ahi[rt][ks] = h; alo[rt][ks] = l;
        }
    }

    u64 bk[2][4];
#pragma unroll
    for (int rt = 0; rt < 2; ++rt)
#pragma unroll
        for (int rg = 0; rg < 4; ++rg) bk[rt][rg] = ~0ull;

#pragma unroll 1
    for (int p = 0; p < 8; ++p) {
        __syncthreads();
        {
            const int4* gsrc = (const int4*)(cbImg + (size_t)p * 65536);
            int4* ldst = (int4*)sB;
#pragma unroll
            for (int it = 0; it < 16; ++it)
                ldst[it * 256 + tid] = gsrc[it * 256 + tid];
        }
        __syncthreads();

        f32x4 acc[2][8] = {};
#pragma unroll
        for (int ks = 0; ks < 4; ++ks) {
#pragma unroll
            for (int ct = 0; ct < 8; ++ct) {
                int cidx = ct * 16 + l15;
                int boff = ((cidx * 128 + ks * 32 + lq * 8) * 2) ^ ((cidx & 7) << 4);
                bf16x8 bh = *(const bf16x8*)((const char*)sB + boff);
                bf16x8 bl = *(const bf16x8*)((const char*)sB + boff + 32768);
#pragma unroll
                for (int rt = 0; rt < 2; ++rt) {
                    acc[rt][ct] = __builtin_amdgcn_mfma_f32_16x16x32_bf16(ahi[rt][ks], bh, acc[rt][ct], 0, 0, 0);
                    acc[rt][ct] = __builtin_amdgcn_mfma_f32_16x16x32_bf16(alo[rt][ks], bh, acc[rt][ct], 0, 0, 0);
                    acc[rt][ct] = __builtin_amdgcn_mfma_f32_16x16x32_bf16(ahi[rt][ks], bl, acc[rt][ct], 0, 0, 0);
                }
            }
        }
#pragma unroll
        for (int rt = 0; rt < 2; ++rt) {
#pragma unroll
            for (int ct = 0; ct < 8; ++ct) {
                int code = p * 128 + ct * 16 + l15;
                float cc = sC2[code];
#pragma unroll
                for (int rg = 0; rg < 4; ++rg) {
                    float z2 = sZ2[wid * 32 + rt * 16 + lq * 4 + rg];
                    float d = (z2 - 2.0f * acc[rt][ct][rg]) + cc;
                    d = fmaxf(d, 0.f);
                    u64 key = ((u64)__float_as_uint(d) << 32) | (unsigned)code;
                    if (key < bk[rt][rg]) bk[rt][rg] = key;
                }
            }
        }
    }

#pragma unroll
    for (int rt = 0; rt < 2; ++rt) {
#pragma unroll
        for (int rg = 0; rg < 4; ++rg) {
            u64 k = bk[rt][rg];
#pragma unroll
            for (int m = 1; m < 16; m <<= 1) {
                u64 o = __shfl_xor(k, m, 64);
                if (o < k) k = o;
            }
            if (l15 == 0)
                sIdx[wid * 32 + rt * 16 + lq * 4 + rg] = (int)(k & 0xffffffffull);
        }
    }
    __syncthreads();

    float lsse = 0.f;
    {
        int row = tid >> 1, half = tid & 1;
        int code = sIdx[row];
        const float* cbrow = cb + (size_t)code * 128 + half * 64;
        const float* zrow  = z + (row0 + row) * 128 + half * 64;
        ush* qrow = q + (row0 + row) * 128 + half * 64;
        for (int j = 0; j < 16; ++j) {
            float4 cv = *(const float4*)(cbrow + j * 4);
            float4 zv = *(const float4*)(zrow + j * 4);
            float d0 = cv.x - zv.x, d1 = cv.y - zv.y;
            float d2 = cv.z - zv.z, d3 = cv.w - zv.w;
            lsse = fmaf(d0, d0, lsse); lsse = fmaf(d1, d1, lsse);
            lsse = fmaf(d2, d2, lsse); lsse = fmaf(d3, d3, lsse);
            ushort4 o;
            o.x = f2bf(zv.x + d0); o.y = f2bf(zv.y + d1);
            o.z = f2bf(zv.z + d2); o.w = f2bf(zv.w + d3);
            *(ushort4*)(qrow + j * 4) = o;
        }
    }
#pragma unroll
    for (int off = 32; off > 0; off >>= 1) lsse += __shfl_down(lsse, off, 64);
    if (lane == 0) sRed[wid] = lsse;
    __syncthreads();
    if (tid == 0) partials[blockIdx.x] = (sRed[0] + sRed[1]) + (sRed[2] + sRed[3]);
}

// ============================ loss finalize ================================
__global__ __launch_bounds__(256) void loss_finish(
    const float* __restrict__ partials, float* __restrict__ outLoss)
{
    __shared__ float sR[256];
    float s = 0.f;
    for (int i = threadIdx.x; i < 1024; i += 256) s += partials[i];
    sR[threadIdx.x] = s;
    __syncthreads();
    for (int st = 128; st > 0; st >>= 1) {
        if (threadIdx.x < st) sR[threadIdx.x] += sR[threadIdx.x + st];
        __syncthreads();
    }
    if (threadIdx.x == 0) {
        float m = sR[0] / 16777216.0f;
        outLoss[0] = m + 0.25f * m;
    }
}

// ============================= launcher ====================================
extern "C" void kernel_launch(void* const* d_in, const int* in_sizes, int n_in,
                              void* d_out, int out_size, void* d_ws, size_t ws_size,
                              hipStream_t stream)
{
    const float* x        = (const float*)d_in[0];
    const float* enc_in_w = (const float*)d_in[1];
    const float* enc_in_b = (const float*)d_in[2];
    const float* rb0_w1   = (const float*)d_in[3];
    const float* rb0_b1   = (const float*)d_in[4];
    const float* rb0_w2   = (const float*)d_in[5];
    const float* rb0_b2   = (const float*)d_in[6];
    const float* rb1_w1   = (const float*)d_in[7];
    const float* rb1_b1   = (const float*)d_in[8];
    const float* rb1_w2   = (const float*)d_in[9];
    const float* rb1_b2   = (const float*)d_in[10];
    const float* rb1_ws   = (const float*)d_in[11];
    const float* rb1_bs   = (const float*)d_in[12];
    const float* down_w   = (const float*)d_in[13];
    const float* down_b   = (const float*)d_in[14];
    const float* codebook = (const float*)d_in[15];
    const float* d1_w1    = (const float*)d_in[16];
    const float* d1_b1    = (const float*)d_in[17];
    const float* d1_w2    = (const float*)d_in[18];
    const float* d1_b2    = (const float*)d_in[19];
    const float* up_w     = (const float*)d_in[20];
    const float* up_b     = (const float*)d_in[21];
    const float* d0_w1    = (const float*)d_in[22];
    const float* d0_b1    = (const float*)d_in[23];
    const float* d0_w2    = (const float*)d_in[24];
    const float* d0_b2    = (const float*)d_in[25];
    const float* out_w    = (const float*)d_in[26];
    const float* out_b    = (const float*)d_in[27];
    (void)in_sizes; (void)n_in; (void)out_size;

    const size_t MB = 1ull << 20;
    char* ws = (char*)d_ws;
    float* partials = (float*)ws;                  // 1024 f32
    float* c2v      = (float*)(ws + 32 * 1024);    // 1024 f32
    float* cbT      = (float*)(ws + 64 * 1024);    // 128x1024 f32 (512 KB)
    char*  cbImg    = ws + 1 * MB;                 // 512 KB split hi/lo image
    ush*   wreg     = (ush*)(ws + 1 * MB + 512 * 1024);

    ush* w_rb0_1 = wreg + 0;
    ush* w_rb0_2 = wreg + 36864;
    ush* w_rb1_1 = wreg + 73728;
    ush* w_rb1_2 = wreg + 147456;
    ush* w_rb1_s = wreg + 294912;
    ush* w_down  = wreg + 303104;
    ush* w_d1_1  = wreg + 450560;
    ush* w_d1_2  = wreg + 598016;
    ush* w_up    = wreg + 745472;
    ush* w_d0_1  = wreg + 819200;
    ush* w_d0_2  = wreg + 856064;
    ush* w_out   = wreg + 892928;

    char* base = ws + 4 * MB;

    int cbn = 8;
    while (cbn > 1 && 4 * MB + (size_t)cbn * 56 * MB > ws_size) cbn >>= 1;

    auto prep = [&](const float* src, ush* dst, int O, int I, int KSp, int Opad) {
        int tot = Opad * KSp * KSp * I;
        prep_w<<<dim3((tot + 255) / 256), 256, 0, stream>>>(src, dst, O, I, KSp, Opad);
    };
    prep(rb0_w1, w_rb0_1, 64, 64, 3, 64);
    prep(rb0_w2, w_rb0_2, 64, 64, 3, 64);
    prep(rb1_w1, w_rb1_1, 128, 64, 3, 128);
    prep(rb1_w2, w_rb1_2, 128, 128, 3, 128);
    prep(rb1_ws, w_rb1_s, 128, 64, 1, 128);
    prep(down_w, w_down, 128, 128, 3, 128);
    prep(d1_w1, w_d1_1, 128, 128, 3, 128);
    prep(d1_w2, w_d1_2, 128, 128, 3, 128);
    prep(up_w, w_up, 64, 128, 3, 64);
    prep(d0_w1, w_d0_1, 64, 64, 3, 64);
    prep(d0_w2, w_d0_2, 64, 64, 3, 64);
    prep(out_w, w_out, 3, 64, 3, 16);

    cb_transpose<<<dim3(512), 256, 0, stream>>>(codebook, cbT);
    cb_c2<<<dim3(4), 256, 0, stream>>>(cbT, c2v);
    prep_cb_split<<<dim3(512), 256, 0, stream>>>(codebook, cbImg);

    for (int e0 = 0; e0 < 8; e0 += cbn) {
        const float* xc   = x + (size_t)e0 * 3 * 65536;
        float*       outc = (float*)d_out + (size_t)e0 * 3 * 65536;

        ush*   h0 = (ush*)(base + (size_t)cbn * 0 * MB);
        ush*   t  = (ush*)(base + (size_t)cbn * 8 * MB);
        ush*   r0 = (ush*)(base + (size_t)cbn * 16 * MB);
        ush*   t1 = (ush*)(base + (size_t)cbn * 24 * MB);
        ush*   r1 = (ush*)(base + (size_t)cbn * 40 * MB);
        float* z  = (float*)(base + (size_t)cbn * 0 * MB);
        ush*   qc = (ush*)(base + (size_t)cbn * 8 * MB);
        ush*   qh = (ush*)(base + (size_t)cbn * 12 * MB);
        ush*   dt = (ush*)(base + (size_t)cbn * 16 * MB);
        ush*   dr = (ush*)(base + (size_t)cbn * 20 * MB);
        ush*   up = (ush*)(base + (size_t)cbn * 24 * MB);
        ush*   u  = (ush*)(base + (size_t)cbn * 40 * MB);
        ush*   t2 = (ush*)(base + (size_t)cbn * 0 * MB);
        ush*   r2 = (ush*)(base + (size_t)cbn * 8 * MB);

        // ---------------- encoder ----------------
        enc_in_k<<<dim3(256, cbn), 256, 0, stream>>>(xc, enc_in_w, enc_in_b, h0);
        mconv<64, 64, 3, 4, true, false><<<dim3(4, 64, cbn), 256, 0, stream>>>(
            h0, w_rb0_1, rb0_b1, nullptr, t, 256, 256);
        mconv<64, 64, 3, 4, true, true><<<dim3(4, 64, cbn), 256, 0, stream>>>(
            t, w_rb0_2, rb0_b2, h0, r0, 256, 256);
        mconv<64, 128, 3, 4, true, false><<<dim3(4, 64, 2 * cbn), 256, 0, stream>>>(
            r0, w_rb1_1, rb1_b1, nullptr, t1, 256, 256);
        mconv<64, 128, 1, 4, false, false><<<dim3(4, 64, 2 * cbn), 256, 0, stream>>>(
            r0, w_rb1_s, rb1_bs, nullptr, r1, 256, 256);
        mconv<128, 128, 3, 2, true, true><<<dim3(4, 128, 2 * cbn), 256, 0, stream>>>(
            t1, w_rb1_2, rb1_b2, r1, r1, 256, 256);
        mconv_s2_z<<<dim3(4, 128, 2 * cbn), 256, 0, stream>>>(
            r1, w_down, down_b, z, 256, 256);

        // ---------------- quantizer ----------------
        vq_mfma<<<dim3(cbn * 128), 256, 0, stream>>>(
            z, codebook, cbImg, c2v, qc, partials + (size_t)e0 * 128);
        transpose_q<<<dim3(cbn * 128), 256, 0, stream>>>(qc, qh);

        // ---------------- decoder ----------------
        mconv<128, 128, 3, 2, true, false><<<dim3(2, 64, 2 * cbn), 256, 0, stream>>>(
            qh, w_d1_1, d1_b1, nullptr, dt, 128, 128);
        mconv<128, 128, 3, 2, true, true><<<dim3(2, 64, 2 * cbn), 256, 0, stream>>>(
            dt, w_d1_2, d1_b2, qh, dr, 128, 128);
        upsample2x_nhwc<<<dim3(cbn * 4096), 256, 0, stream>>>(dr, up);
        mconv<128, 64, 3, 2, true, false><<<dim3(4, 128, cbn), 256, 0, stream>>>(
            up, w_up, up_b, nullptr, u, 256, 256);
        mconv<64, 64, 3, 4, true, false><<<dim3(4, 64, cbn), 256, 0, stream>>>(
            u, w_d0_1, d0_b1, nullptr, t2, 256, 256);
        mconv<64, 64, 3, 4, true, true><<<dim3(4, 64, cbn), 256, 0, stream>>>(
            t2, w_d0_2, d0_b2, u, r2, 256, 256);
        mconv_out<<<dim3(4, 64, cbn), 256, 0, stream>>>(
            r2, w_out, out_b, outc, 256, 256);
    }

    // ---------------- loss ----------------
    loss_finish<<<dim3(1), 256, 0, stream>>>(partials, (float*)d_out + 1572864);
}

// Round 8
// 1789.058 us; speedup vs baseline: 1.8635x; 1.0524x over previous
//
#include <hip/hip_runtime.h>

// ---------------------------------------------------------------------------
// VQ-VAE forward: bf16 MFMA implicit-GEMM convs (NHWC) + split-bf16 MFMA VQ.
// R8: XCD-aware bijective block swizzle (y-banded) so each XCD's L2 holds a
// contiguous y-band working set (~4MB) instead of the whole stream (32MB).
// ---------------------------------------------------------------------------

typedef float    f32x4  __attribute__((ext_vector_type(4)));
typedef short    bf16x8 __attribute__((ext_vector_type(8)));
typedef int      i32x4  __attribute__((ext_vector_type(4)));
typedef unsigned short ush;
typedef unsigned long long u64;

__device__ __forceinline__ ush f2bf(float f) {
    unsigned u = __float_as_uint(f);
    u += 0x7fff + ((u >> 16) & 1);          // round-to-nearest-even
    return (ush)(u >> 16);
}
__device__ __forceinline__ float bf2f(ush h) {
    return __uint_as_float(((unsigned)h) << 16);
}
__device__ __forceinline__ i32x4 ntld4(const void* p) {
    return __builtin_nontemporal_load((const i32x4*)p);
}

// XCD-aware swizzle: lin' = (lin%8)*(N/8) + lin/8 (N%8==0 at all call sites),
// decoded y-slowest so each XCD owns a contiguous y-band (x fastest, then z).
__device__ __forceinline__ void swz_coords(int& bx, int& by, int& bz) {
    const int X = gridDim.x, Z = gridDim.z;
    int lin = blockIdx.x + X * (blockIdx.y + gridDim.y * blockIdx.z);
    const int N = X * gridDim.y * Z;
    lin = (lin & 7) * (N >> 3) + (lin >> 3);
    bx = lin % X;
    int r = lin / X;
    bz = r % Z;
    by = r / Z;
}

// ========== weight repack OIHW f32 -> kxy-major bf16 [kxy][o][i] ===========
__global__ void prep_w(const float* __restrict__ src, ush* __restrict__ dst,
                       int O, int I, int KS, int Opad)
{
    int idx = blockIdx.x * 256 + threadIdx.x;
    if (idx >= Opad * KS * KS * I) return;
    int ci  = idx % I;
    int rem = idx / I;
    int o   = rem % Opad;
    int kxy = rem / Opad;
    int kx = kxy % KS, ky = kxy / KS;
    float v = 0.f;
    if (o < O) v = src[((size_t)(o * I + ci) * KS + ky) * KS + kx];
    dst[((size_t)kxy * Opad + o) * I + ci] = f2bf(v);
}

// ============ codebook split hi/lo, pre-swizzled LDS image =================
__global__ void prep_cb_split(const float* __restrict__ cb, char* __restrict__ img)
{
    int idx = blockIdx.x * 256 + threadIdx.x;   // 1024*128
    if (idx >= 1024 * 128) return;
    int k = idx >> 7, e = idx & 127;
    int chunk = k >> 7, cidx = k & 127;
    float c = cb[idx];
    ush hi = f2bf(c);
    ush lo = f2bf(c - bf2f(hi));
    int boff = (((cidx * 128) + e) * 2) ^ ((cidx & 7) << 4);
    char* base = img + (size_t)chunk * 65536;
    *(ush*)(base + boff) = hi;
    *(ush*)(base + boff + 32768) = lo;
}

// ===================== enc_in: 3->64, NCHW f32 in -> NHWC bf16 out =========
__global__ __launch_bounds__(256) void enc_in_k(
    const float* __restrict__ x, const float* __restrict__ w,
    const float* __restrict__ bias, ush* __restrict__ out)
{
    __shared__ float sX[3][3][260];
    __shared__ float sW[27][64];
    __shared__ float sB[64];
    const int tid = threadIdx.x;
    const int y = blockIdx.x, b = blockIdx.y;

    for (int i = tid; i < 3 * 3 * 258; i += 256) {
        int xi = i % 258;
        int r  = (i / 258) % 3;
        int c  = i / 774;
        int gy = y + r - 1, gx = xi - 1;
        float v = 0.f;
        if ((unsigned)gy < 256u && (unsigned)gx < 256u)
            v = x[(((size_t)b * 3 + c) * 256 + gy) * 256 + gx];
        sX[c][r][xi] = v;
    }
    for (int i = tid; i < 1728; i += 256) {
        int co = i & 63, k = i >> 6;
        int c = k % 3, kxy = k / 3;
        int kx = kxy % 3, ky = kxy / 3;
        sW[k][co] = w[co * 27 + c * 9 + ky * 3 + kx];
    }
    if (tid < 64) sB[tid] = bias[tid];
    __syncthreads();

    float acc[64];
#pragma unroll
    for (int c = 0; c < 64; ++c) acc[c] = 0.f;
    const int px = tid;
#pragma unroll
    for (int k = 0; k < 27; ++k) {
        const int c = k % 3, kxy = k / 3;
        const int kx = kxy % 3, ky = kxy / 3;
        float iv = sX[c][ky][px + kx];
#pragma unroll
        for (int co = 0; co < 64; ++co) acc[co] = fmaf(iv, sW[k][co], acc[co]);
    }
    ush* op = out + (((size_t)b * 256 + y) * 256 + px) * 64;
#pragma unroll
    for (int c8 = 0; c8 < 8; ++c8) {
        ush tmp[8];
#pragma unroll
        for (int j = 0; j < 8; ++j) tmp[j] = f2bf(acc[c8 * 8 + j] + sB[c8 * 8 + j]);
        *(int4*)(op + c8 * 8) = *(const int4*)tmp;
    }
}

// ===================== MFMA conv, stride 1, NHWC bf16 ======================
// Block: 64 cout x 64 px x ROWS rows, 4 waves. Per kxy: 8KB weight slab
// double-buffered in LDS (issue-early/write-late); K-loop is LDS-only.
template<int CIN, int COUT, int KS, int ROWS, bool RELU, bool ADD>
__global__ __launch_bounds__(256) void mconv(
    const ush* __restrict__ in, const ush* __restrict__ wt,
    const float* __restrict__ bias, const ush* __restrict__ res,
    ush* __restrict__ out, int H, int W)
{
    constexpr int HALO  = KS / 2;
    constexpr int XW    = 64 + 2 * HALO;
    constexpr int COB   = COUT / 64;
    constexpr int SROWS = ROWS + 2 * HALO;
    constexpr int F     = ROWS;
    constexpr int WPR   = 4 / ROWS;
    constexpr int CP    = (CIN > 64) ? 2 : 1;
    constexpr int CC    = CIN / CP;
    constexpr int KK    = KS * KS;

    __shared__ ush sIn[SROWS * XW * CC];
    __shared__ ush sW[2][64 * CC];

    int bx, by, bz;
    swz_coords(bx, by, bz);
    const int tid = threadIdx.x;
    const int b   = bz / COB;
    const int co0 = (bz % COB) * 64;
    const int y0  = by * ROWS;
    const int x0  = bx * 64;

    const int lane = tid & 63, wid = tid >> 6;
    const int r   = wid / WPR;
    const int fb  = (wid % WPR) * F;
    const int l15 = lane & 15, lq = lane >> 4;

    // this thread's two weight chunks (512 x 16B per slab)
    const int co_a0 = tid >> 3,           ci8_a = tid & 7;
    const int co_b0 = (tid + 256) >> 3,   ci8_b = tid & 7;
    const int wdstA = ((co_a0 * CC + ci8_a * 8) * 2) ^ ((co_a0 & 7) << 4);
    const int wdstB = ((co_b0 * CC + ci8_b * 8) * 2) ^ ((co_b0 & 7) << 4);

    f32x4 acc[4][F] = {};

#pragma unroll 1
    for (int ph = 0; ph < CP; ++ph) {
        if (ph) __syncthreads();
        // ---- input stage (NT loads, XOR swizzle) ----
        constexpr int CHUNKS = SROWS * XW * CC / 8;
        for (int i = tid; i < CHUNKS; i += 256) {
            int ci8 = i % (CC / 8);
            int r2  = i / (CC / 8);
            int xi  = r2 % XW;
            int row = r2 / XW;
            int gy = y0 + row - HALO;
            int gx = x0 + xi - HALO;
            i32x4 v = {0, 0, 0, 0};
            if ((unsigned)gy < (unsigned)H && (unsigned)gx < (unsigned)W)
                v = ntld4(in + (((size_t)b * H + gy) * W + gx) * CIN + ph * CC + ci8 * 8);
            int bo = ((row * XW + xi) * CC + ci8 * 8) * 2;
            *(i32x4*)((char*)sIn + (bo ^ ((xi & 7) << 4))) = v;
        }
        // ---- weight prologue: kxy=0 -> buf0 ----
        {
            const ush* slab = wt + (size_t)co0 * CIN + ph * CC;
            i32x4 v0 = *(const i32x4*)(slab + (size_t)co_a0 * CIN + ci8_a * 8);
            i32x4 v1 = *(const i32x4*)(slab + (size_t)co_b0 * CIN + ci8_b * 8);
            *(i32x4*)((char*)sW[0] + wdstA) = v0;
            *(i32x4*)((char*)sW[0] + wdstB) = v1;
        }
        __syncthreads();

        int curb = 0;
#pragma unroll 1
        for (int kxy = 0; kxy < KK; ++kxy) {
            const int kx = kxy % KS, ky = kxy / KS;
            i32x4 w0, w1;
            const bool hn = (kxy + 1 < KK);
            if (hn) {
                const ush* slab = wt + ((size_t)(kxy + 1) * COUT + co0) * CIN + ph * CC;
                w0 = *(const i32x4*)(slab + (size_t)co_a0 * CIN + ci8_a * 8);
                w1 = *(const i32x4*)(slab + (size_t)co_b0 * CIN + ci8_b * 8);
            }
#pragma unroll
            for (int kb2 = 0; kb2 < CC / 32; ++kb2) {
                const int cip0 = kb2 * 32;
                bf16x8 a[4];
#pragma unroll
                for (int m = 0; m < 4; ++m) {
                    const int coa = m * 16 + l15;
                    a[m] = *(const bf16x8*)((const char*)sW[curb] +
                           (((coa * CC + cip0 + lq * 8) * 2) ^ ((coa & 7) << 4)));
                }
#pragma unroll
                for (int n = 0; n < F; ++n) {
                    const int xi = (fb + n) * 16 + l15 + kx;
                    const int bo = (((r + ky) * XW + xi) * CC + cip0 + lq * 8) * 2;
                    bf16x8 bv = *(const bf16x8*)((const char*)sIn + (bo ^ ((xi & 7) << 4)));
#pragma unroll
                    for (int m = 0; m < 4; ++m)
                        acc[m][n] = __builtin_amdgcn_mfma_f32_16x16x32_bf16(a[m], bv, acc[m][n], 0, 0, 0);
                }
            }
            if (hn) {
                *(i32x4*)((char*)sW[curb ^ 1] + wdstA) = w0;
                *(i32x4*)((char*)sW[curb ^ 1] + wdstB) = w1;
            }
            __syncthreads();
            curb ^= 1;
        }
    }

    const int y = y0 + r;
#pragma unroll
    for (int m = 0; m < 4; ++m) {
        const int com = co0 + m * 16 + lq * 4;
        float4 bvv = *(const float4*)(bias + com);
#pragma unroll
        for (int n = 0; n < F; ++n) {
            const int px = x0 + (fb + n) * 16 + l15;
            size_t oaddr = (((size_t)b * H + y) * W + px) * COUT + com;
            float v0 = acc[m][n][0] + bvv.x;
            float v1 = acc[m][n][1] + bvv.y;
            float v2 = acc[m][n][2] + bvv.z;
            float v3 = acc[m][n][3] + bvv.w;
            if constexpr (ADD) {
                ushort4 rv = *(const ushort4*)(res + oaddr);
                v0 += bf2f(rv.x); v1 += bf2f(rv.y);
                v2 += bf2f(rv.z); v3 += bf2f(rv.w);
            }
            if constexpr (RELU) {
                v0 = fmaxf(v0, 0.f); v1 = fmaxf(v1, 0.f);
                v2 = fmaxf(v2, 0.f); v3 = fmaxf(v3, 0.f);
            }
            ushort4 o;
            o.x = f2bf(v0); o.y = f2bf(v1); o.z = f2bf(v2); o.w = f2bf(v3);
            *(ushort4*)(out + oaddr) = o;
        }
    }
}

// ============ MFMA conv 3x3 stride 2 (128->128), out z NCHW fp32 ===========
__global__ __launch_bounds__(256) void mconv_s2_z(
    const ush* __restrict__ in, const ush* __restrict__ wt,
    const float* __restrict__ bias, float* __restrict__ zout, int Hi, int Wi)
{
    constexpr int CIN = 128, COUT = 128, XW = 66, CC = 64;
    __shared__ ush sIn[3 * XW * CC];
    __shared__ ush sW[2][64 * CC];
    const int Ho = Hi >> 1, Wo = Wi >> 1;
    int bx, by, bz;
    swz_coords(bx, by, bz);
    const int tid = threadIdx.x;
    const int b = bz >> 1, co0 = (bz & 1) * 64;
    const int yo = by, xo0 = bx * 32;

    const int lane = tid & 63, wid = tid >> 6;
    const int wm = wid >> 1, wn = wid & 1;
    const int l15 = lane & 15, lq = lane >> 4;
    const int pxl = wn * 16 + l15;

    const int co_a0 = tid >> 3,         ci8_a = tid & 7;
    const int co_b0 = (tid + 256) >> 3, ci8_b = tid & 7;
    const int wdstA = ((co_a0 * CC + ci8_a * 8) * 2) ^ ((co_a0 & 7) << 4);
    const int wdstB = ((co_b0 * CC + ci8_b * 8) * 2) ^ ((co_b0 & 7) << 4);

    f32x4 acc[2] = {};

#pragma unroll 1
    for (int ph = 0; ph < 2; ++ph) {
        if (ph) __syncthreads();
        for (int i = tid; i < 3 * XW * CC / 8; i += 256) {
            int ci8 = i & 7;
            int r2  = i >> 3;
            int xi  = r2 % XW;
            int row = r2 / XW;
            int gy = 2 * yo + row - 1, gx = 2 * xo0 + xi - 1;
            i32x4 v = {0, 0, 0, 0};
            if ((unsigned)gy < (unsigned)Hi && (unsigned)gx < (unsigned)Wi)
                v = ntld4(in + (((size_t)b * Hi + gy) * Wi + gx) * CIN + ph * CC + ci8 * 8);
            int bo = ((row * XW + xi) * CC + ci8 * 8) * 2;
            *(i32x4*)((char*)sIn + (bo ^ ((xi & 7) << 4))) = v;
        }
        {
            const ush* slab = wt + (size_t)co0 * CIN + ph * CC;
            i32x4 v0 = *(const i32x4*)(slab + (size_t)co_a0 * CIN + ci8_a * 8);
            i32x4 v1 = *(const i32x4*)(slab + (size_t)co_b0 * CIN + ci8_b * 8);
            *(i32x4*)((char*)sW[0] + wdstA) = v0;
            *(i32x4*)((char*)sW[0] + wdstB) = v1;
        }
        __syncthreads();

        int curb = 0;
#pragma unroll 1
        for (int kxy = 0; kxy < 9; ++kxy) {
            const int kx = kxy % 3, ky = kxy / 3;
            i32x4 w0, w1;
            const bool hn = (kxy + 1 < 9);
            if (hn) {
                const ush* slab = wt + ((size_t)(kxy + 1) * COUT + co0) * CIN + ph * CC;
                w0 = *(const i32x4*)(slab + (size_t)co_a0 * CIN + ci8_a * 8);
                w1 = *(const i32x4*)(slab + (size_t)co_b0 * CIN + ci8_b * 8);
            }
#pragma unroll
            for (int kb2 = 0; kb2 < 2; ++kb2) {
                const int cip0 = kb2 * 32;
                bf16x8 a[2];
#pragma unroll
                for (int m = 0; m < 2; ++m) {
                    const int coa = wm * 32 + m * 16 + l15;
                    a[m] = *(const bf16x8*)((const char*)sW[curb] +
                           (((coa * CC + cip0 + lq * 8) * 2) ^ ((coa & 7) << 4)));
                }
                const int xl = 2 * pxl + kx;
                const int bo = ((ky * XW + xl) * CC + cip0 + lq * 8) * 2;
                bf16x8 bfr = *(const bf16x8*)((const char*)sIn + (bo ^ ((xl & 7) << 4)));
                acc[0] = __builtin_amdgcn_mfma_f32_16x16x32_bf16(a[0], bfr, acc[0], 0, 0, 0);
                acc[1] = __builtin_amdgcn_mfma_f32_16x16x32_bf16(a[1], bfr, acc[1], 0, 0, 0);
            }
            if (hn) {
                *(i32x4*)((char*)sW[curb ^ 1] + wdstA) = w0;
                *(i32x4*)((char*)sW[curb ^ 1] + wdstB) = w1;
            }
            __syncthreads();
            curb ^= 1;
        }
    }

    const int px = xo0 + pxl;
#pragma unroll
    for (int m = 0; m < 2; ++m) {
        const int com = co0 + wm * 32 + m * 16 + lq * 4;
        float4 bv = *(const float4*)(bias + com);
#pragma unroll
        for (int r = 0; r < 4; ++r) {
            float v = acc[m][r] + ((const float*)&bv)[r];
            v = fmaxf(v, 0.f);
            zout[(((size_t)b * COUT + com + r) * Ho + yo) * Wo + px] = v;
        }
    }
}

// ============ final conv 64->3, NHWC bf16 in -> NCHW f32 d_out =============
__global__ __launch_bounds__(256) void mconv_out(
    const ush* __restrict__ in, const ush* __restrict__ wt,
    const float* __restrict__ bias, float* __restrict__ outv, int H, int W)
{
    constexpr int K32 = 18, XW = 66, SROWS = 6;
    __shared__ ush sIn[SROWS * XW * 64];
    int bx, by, bz;
    swz_coords(bx, by, bz);
    const int tid = threadIdx.x;
    const int b = bz, y0 = by * 4, x0 = bx * 64;

    for (int i = tid; i < SROWS * XW * 64 / 8; i += 256) {
        int ci8 = i & 7;
        int r2  = i >> 3;
        int xi  = r2 % XW;
        int row = r2 / XW;
        int gy = y0 + row - 1, gx = x0 + xi - 1;
        i32x4 v = {0, 0, 0, 0};
        if ((unsigned)gy < (unsigned)H && (unsigned)gx < (unsigned)W)
            v = ntld4(in + (((size_t)b * H + gy) * W + gx) * 64 + ci8 * 8);
        int bo = ((row * XW + xi) * 64 + ci8 * 8) * 2;
        *(i32x4*)((char*)sIn + (bo ^ ((xi & 7) << 4))) = v;
    }
    __syncthreads();

    const int lane = tid & 63, wid = tid >> 6;
    const int l15 = lane & 15, lq = lane >> 4;
    const int r = wid;

    f32x4 acc[4] = {};

#pragma unroll
    for (int kb = 0; kb < K32; ++kb) {
        const int k0 = kb * 32;
        const int ci0 = k0 % 64;
        const int kxy = k0 / 64;
        const int kx = kxy % 3, ky = kxy / 3;
        // kxy-major layout: [kxy][16][64]
        bf16x8 a0 = *(const bf16x8*)(wt + ((size_t)kxy * 16 + l15) * 64 + ci0 + lq * 8);
#pragma unroll
        for (int n = 0; n < 4; ++n) {
            const int xi = n * 16 + l15 + kx;
            const int bo = (((r + ky) * XW + xi) * 64 + ci0 + lq * 8) * 2;
            bf16x8 bfr = *(const bf16x8*)((const char*)sIn + (bo ^ ((xi & 7) << 4)));
            acc[n] = __builtin_amdgcn_mfma_f32_16x16x32_bf16(a0, bfr, acc[n], 0, 0, 0);
        }
    }

    const int y = y0 + r;
    if (lq == 0) {
#pragma unroll
        for (int n = 0; n < 4; ++n) {
            const int px = x0 + n * 16 + l15;
#pragma unroll
            for (int ch = 0; ch < 3; ++ch)
                outv[(((size_t)b * 3 + ch) * H + y) * W + px] = acc[n][ch] + bias[ch];
        }
    }
}

// ============== q transpose: NCHW bf16 -> NHWC bf16 (C=H=W=128) ============
__global__ __launch_bounds__(256) void transpose_q(
    const ush* __restrict__ qc, ush* __restrict__ qh)
{
    __shared__ ush sT[128][136];
    const int tid = threadIdx.x;
    const int b = blockIdx.x >> 7, h = blockIdx.x & 127;

    for (int i = tid; i < 2048; i += 256) {
        int c = i >> 4, w8 = i & 15;
        int4 v = *(const int4*)(qc + (((size_t)b * 128 + c) * 128 + h) * 128 + w8 * 8);
        const ush* pv = (const ush*)&v;
#pragma unroll
        for (int j = 0; j < 8; ++j) sT[w8 * 8 + j][c] = pv[j];
    }
    __syncthreads();
    for (int i = tid; i < 2048; i += 256) {
        int w = i >> 4, c8 = i & 15;
        int4 v;
        ush* pv = (ush*)&v;
#pragma unroll
        for (int j = 0; j < 8; ++j) pv[j] = sT[w][c8 * 8 + j];
        *(int4*)(qh + (((size_t)b * 128 + h) * 128 + w) * 128 + c8 * 8) = v;
    }
}

// ================= nearest 2x upsample, NHWC bf16 (C=128) ==================
__global__ void upsample2x_nhwc(const ush* __restrict__ in, ush* __restrict__ out)
{
    long idx = (long)blockIdx.x * 256 + threadIdx.x;
    int c8 = (int)(idx & 15);
    int xx = (int)((idx >> 4) & 255);
    int yy = (int)((idx >> 12) & 255);
    int b  = (int)(idx >> 20);
    int4 v = *(const int4*)(in + (((size_t)b * 128 + (yy >> 1)) * 128 + (xx >> 1)) * 128 + c8 * 8);
    *(int4*)(out + (((size_t)b * 256 + yy) * 256 + xx) * 128 + c8 * 8) = v;
}

// ========================= codebook c^2 ====================================
__global__ void cb_transpose(const float* __restrict__ cb, float* __restrict__ cbT)
{
    int idx = blockIdx.x * 256 + threadIdx.x;
    if (idx < 1024 * 128) {
        int k = idx >> 7, e = idx & 127;
        cbT[e * 1024 + k] = cb[idx];
    }
}

__global__ void cb_c2(const float* __restrict__ cbT, float* __restrict__ c2)
{
    int k = blockIdx.x * 256 + threadIdx.x;
    if (k < 1024) {
        float s = 0.f;
        for (int e = 0; e < 128; ++e) {
            float v = cbT[e * 1024 + k];
            s = fmaf(v, v, s);
        }
        c2[k] = s;
    }
}

// ===================== MFMA quantizer ======================================
__global__ __launch_bounds__(256) void vq_mfma(
    const float* __restrict__ z, const float* __restrict__ cb,
    const char* __restrict__ cbImg, const float* __restrict__ c2,
    ush* __restrict__ q, float* __restrict__ partials)
{
    __shared__ ush   sB[32768];        // 64 KB codebook chunk (hi|lo)
    __shared__ float sC2[1024];
    __shared__ float sZ2p[128][2];
    __shared__ float sZ2[128];
    __shared__ int   sIdx[128];
    __shared__ float sRed[4];

    const int tid = threadIdx.x;
    const int wid = tid >> 6, lane = tid & 63;
    const int l15 = lane & 15, lq = lane >> 4;
    const size_t row0 = (size_t)blockIdx.x * 128;

    for (int i = tid; i < 1024; i += 256) sC2[i] = c2[i];

    {
        int row = tid >> 1, half = tid & 1;
        const float* zp = z + (row0 + row) * 128 + half * 64;
        float s = 0.f;
        for (int j = 0; j < 16; ++j) {
            float4 v = *(const float4*)(zp + j * 4);
            s = fmaf(v.x, v.x, s); s = fmaf(v.y, v.y, s);
            s = fmaf(v.z, v.z, s); s = fmaf(v.w, v.w, s);
        }
        sZ2p[row][half] = s;
    }
    __syncthreads();
    if (tid < 128) sZ2[tid] = sZ2p[tid][0] + sZ2p[tid][1];

    bf16x8 ahi[2][4], alo[2][4];
#pragma unroll
    for (int rt = 0; rt < 2; ++rt) {
#pragma unroll
        for (int ks = 0; ks < 4; ++ks) {
            const float* zp = z + (row0 + wid * 32 + rt * 16 + l15) * 128 + ks * 32 + lq * 8;
            float4 v0 = *(const float4*)zp;
            float4 v1 = *(const float4*)(zp + 4);
            float f[8] = {v0.x, v0.y, v0.z, v0.w, v1.x, v1.y, v1.z, v1.w};
            bf16x8 h, l;
#pragma unroll
            for (int j = 0; j < 8; ++j) {
                ush hb = f2bf(f[j]);
                h[j] = (short)hb;
                l[j] = (short)f2bf(f[j] - bf2f(hb));
            }
            ahi[rt][ks] = h; alo[rt][ks] = l;
        }
    }

    u64 bk[2][4];
#pragma unroll
    for (int rt = 0; rt < 2; ++rt)
#pragma unroll
        for (int rg = 0; rg < 4; ++rg) bk[rt][rg] = ~0ull;

#pragma unroll 1
    for (int p = 0; p < 8; ++p) {
        __syncthreads();
        {
            const int4* gsrc = (const int4*)(cbImg + (size_t)p * 65536);
            int4* ldst = (int4*)sB;
#pragma unroll
            for (int it = 0; it < 16; ++it)
                ldst[it * 256 + tid] = gsrc[it * 256 + tid];
        }
        __syncthreads();

        f32x4 acc[2][8] = {};
#pragma unroll
        for (int ks = 0; ks < 4; ++ks) {
#pragma unroll
            for (int ct = 0; ct < 8; ++ct) {
                int cidx = ct * 16 + l15;
                int boff = ((cidx * 128 + ks * 32 + lq * 8) * 2) ^ ((cidx & 7) << 4);
                bf16x8 bh = *(const bf16x8*)((const char*)sB + boff);
                bf16x8 bl = *(const bf16x8*)((const char*)sB + boff + 32768);
#pragma unroll
                for (int rt = 0; rt < 2; ++rt) {
                    acc[rt][ct] = __builtin_amdgcn_mfma_f32_16x16x32_bf16(ahi[rt][ks], bh, acc[rt][ct], 0, 0, 0);
                    acc[rt][ct] = __builtin_amdgcn_mfma_f32_16x16x32_bf16(alo[rt][ks], bh, acc[rt][ct], 0, 0, 0);
                    acc[rt][ct] = __builtin_amdgcn_mfma_f32_16x16x32_bf16(ahi[rt][ks], bl, acc[rt][ct], 0, 0, 0);
                }
            }
        }
#pragma unroll
        for (int rt = 0; rt < 2; ++rt) {
#pragma unroll
            for (int ct = 0; ct < 8; ++ct) {
                int code = p * 128 + ct * 16 + l15;
                float cc = sC2[code];
#pragma unroll
                for (int rg = 0; rg < 4; ++rg) {
                    float z2 = sZ2[wid * 32 + rt * 16 + lq * 4 + rg];
                    float d = (z2 - 2.0f * acc[rt][ct][rg]) + cc;
                    d = fmaxf(d, 0.f);
                    u64 key = ((u64)__float_as_uint(d) << 32) | (unsigned)code;
                    if (key < bk[rt][rg]) bk[rt][rg] = key;
                }
            }
        }
    }

#pragma unroll
    for (int rt = 0; rt < 2; ++rt) {
#pragma unroll
        for (int rg = 0; rg < 4; ++rg) {
            u64 k = bk[rt][rg];
#pragma unroll
            for (int m = 1; m < 16; m <<= 1) {
                u64 o = __shfl_xor(k, m, 64);
                if (o < k) k = o;
            }
            if (l15 == 0)
                sIdx[wid * 32 + rt * 16 + lq * 4 + rg] = (int)(k & 0xffffffffull);
        }
    }
    __syncthreads();

    float lsse = 0.f;
    {
        int row = tid >> 1, half = tid & 1;
        int code = sIdx[row];
        const float* cbrow = cb + (size_t)code * 128 + half * 64;
        const float* zrow  = z + (row0 + row) * 128 + half * 64;
        ush* qrow = q + (row0 + row) * 128 + half * 64;
        for (int j = 0; j < 16; ++j) {
            float4 cv = *(const float4*)(cbrow + j * 4);
            float4 zv = *(const float4*)(zrow + j * 4);
            float d0 = cv.x - zv.x, d1 = cv.y - zv.y;
            float d2 = cv.z - zv.z, d3 = cv.w - zv.w;
            lsse = fmaf(d0, d0, lsse); lsse = fmaf(d1, d1, lsse);
            lsse = fmaf(d2, d2, lsse); lsse = fmaf(d3, d3, lsse);
            ushort4 o;
            o.x = f2bf(zv.x + d0); o.y = f2bf(zv.y + d1);
            o.z = f2bf(zv.z + d2); o.w = f2bf(zv.w + d3);
            *(ushort4*)(qrow + j * 4) = o;
        }
    }
#pragma unroll
    for (int off = 32; off > 0; off >>= 1) lsse += __shfl_down(lsse, off, 64);
    if (lane == 0) sRed[wid] = lsse;
    __syncthreads();
    if (tid == 0) partials[blockIdx.x] = (sRed[0] + sRed[1]) + (sRed[2] + sRed[3]);
}

// ============================ loss finalize ================================
__global__ __launch_bounds__(256) void loss_finish(
    const float* __restrict__ partials, float* __restrict__ outLoss)
{
    __shared__ float sR[256];
    float s = 0.f;
    for (int i = threadIdx.x; i < 1024; i += 256) s += partials[i];
    sR[threadIdx.x] = s;
    __syncthreads();
    for (int st = 128; st > 0; st >>= 1) {
        if (threadIdx.x < st) sR[threadIdx.x] += sR[threadIdx.x + st];
        __syncthreads();
    }
    if (threadIdx.x == 0) {
        float m = sR[0] / 16777216.0f;
        outLoss[0] = m + 0.25f * m;
    }
}

// ============================= launcher ====================================
extern "C" void kernel_launch(void* const* d_in, const int* in_sizes, int n_in,
                              void* d_out, int out_size, void* d_ws, size_t ws_size,
                              hipStream_t stream)
{
    const float* x        = (const float*)d_in[0];
    const float* enc_in_w = (const float*)d_in[1];
    const float* enc_in_b = (const float*)d_in[2];
    const float* rb0_w1   = (const float*)d_in[3];
    const float* rb0_b1   = (const float*)d_in[4];
    const float* rb0_w2   = (const float*)d_in[5];
    const float* rb0_b2   = (const float*)d_in[6];
    const float* rb1_w1   = (const float*)d_in[7];
    const float* rb1_b1   = (const float*)d_in[8];
    const float* rb1_w2   = (const float*)d_in[9];
    const float* rb1_b2   = (const float*)d_in[10];
    const float* rb1_ws   = (const float*)d_in[11];
    const float* rb1_bs   = (const float*)d_in[12];
    const float* down_w   = (const float*)d_in[13];
    const float* down_b   = (const float*)d_in[14];
    const float* codebook = (const float*)d_in[15];
    const float* d1_w1    = (const float*)d_in[16];
    const float* d1_b1    = (const float*)d_in[17];
    const float* d1_w2    = (const float*)d_in[18];
    const float* d1_b2    = (const float*)d_in[19];
    const float* up_w     = (const float*)d_in[20];
    const float* up_b     = (const float*)d_in[21];
    const float* d0_w1    = (const float*)d_in[22];
    const float* d0_b1    = (const float*)d_in[23];
    const float* d0_w2    = (const float*)d_in[24];
    const float* d0_b2    = (const float*)d_in[25];
    const float* out_w    = (const float*)d_in[26];
    const float* out_b    = (const float*)d_in[27];
    (void)in_sizes; (void)n_in; (void)out_size;

    const size_t MB = 1ull << 20;
    char* ws = (char*)d_ws;
    float* partials = (float*)ws;                  // 1024 f32
    float* c2v      = (float*)(ws + 32 * 1024);    // 1024 f32
    float* cbT      = (float*)(ws + 64 * 1024);    // 128x1024 f32 (512 KB)
    char*  cbImg    = ws + 1 * MB;                 // 512 KB split hi/lo image
    ush*   wreg     = (ush*)(ws + 1 * MB + 512 * 1024);

    ush* w_rb0_1 = wreg + 0;
    ush* w_rb0_2 = wreg + 36864;
    ush* w_rb1_1 = wreg + 73728;
    ush* w_rb1_2 = wreg + 147456;
    ush* w_rb1_s = wreg + 294912;
    ush* w_down  = wreg + 303104;
    ush* w_d1_1  = wreg + 450560;
    ush* w_d1_2  = wreg + 598016;
    ush* w_up    = wreg + 745472;
    ush* w_d0_1  = wreg + 819200;
    ush* w_d0_2  = wreg + 856064;
    ush* w_out   = wreg + 892928;

    char* base = ws + 4 * MB;

    int cbn = 8;
    while (cbn > 1 && 4 * MB + (size_t)cbn * 56 * MB > ws_size) cbn >>= 1;

    auto prep = [&](const float* src, ush* dst, int O, int I, int KSp, int Opad) {
        int tot = Opad * KSp * KSp * I;
        prep_w<<<dim3((tot + 255) / 256), 256, 0, stream>>>(src, dst, O, I, KSp, Opad);
    };
    prep(rb0_w1, w_rb0_1, 64, 64, 3, 64);
    prep(rb0_w2, w_rb0_2, 64, 64, 3, 64);
    prep(rb1_w1, w_rb1_1, 128, 64, 3, 128);
    prep(rb1_w2, w_rb1_2, 128, 128, 3, 128);
    prep(rb1_ws, w_rb1_s, 128, 64, 1, 128);
    prep(down_w, w_down, 128, 128, 3, 128);
    prep(d1_w1, w_d1_1, 128, 128, 3, 128);
    prep(d1_w2, w_d1_2, 128, 128, 3, 128);
    prep(up_w, w_up, 64, 128, 3, 64);
    prep(d0_w1, w_d0_1, 64, 64, 3, 64);
    prep(d0_w2, w_d0_2, 64, 64, 3, 64);
    prep(out_w, w_out, 3, 64, 3, 16);

    cb_transpose<<<dim3(512), 256, 0, stream>>>(codebook, cbT);
    cb_c2<<<dim3(4), 256, 0, stream>>>(cbT, c2v);
    prep_cb_split<<<dim3(512), 256, 0, stream>>>(codebook, cbImg);

    for (int e0 = 0; e0 < 8; e0 += cbn) {
        const float* xc   = x + (size_t)e0 * 3 * 65536;
        float*       outc = (float*)d_out + (size_t)e0 * 3 * 65536;

        ush*   h0 = (ush*)(base + (size_t)cbn * 0 * MB);
        ush*   t  = (ush*)(base + (size_t)cbn * 8 * MB);
        ush*   r0 = (ush*)(base + (size_t)cbn * 16 * MB);
        ush*   t1 = (ush*)(base + (size_t)cbn * 24 * MB);
        ush*   r1 = (ush*)(base + (size_t)cbn * 40 * MB);
        float* z  = (float*)(base + (size_t)cbn * 0 * MB);
        ush*   qc = (ush*)(base + (size_t)cbn * 8 * MB);
        ush*   qh = (ush*)(base + (size_t)cbn * 12 * MB);
        ush*   dt = (ush*)(base + (size_t)cbn * 16 * MB);
        ush*   dr = (ush*)(base + (size_t)cbn * 20 * MB);
        ush*   up = (ush*)(base + (size_t)cbn * 24 * MB);
        ush*   u  = (ush*)(base + (size_t)cbn * 40 * MB);
        ush*   t2 = (ush*)(base + (size_t)cbn * 0 * MB);
        ush*   r2 = (ush*)(base + (size_t)cbn * 8 * MB);

        // ---------------- encoder ----------------
        enc_in_k<<<dim3(256, cbn), 256, 0, stream>>>(xc, enc_in_w, enc_in_b, h0);
        mconv<64, 64, 3, 4, true, false><<<dim3(4, 64, cbn), 256, 0, stream>>>(
            h0, w_rb0_1, rb0_b1, nullptr, t, 256, 256);
        mconv<64, 64, 3, 4, true, true><<<dim3(4, 64, cbn), 256, 0, stream>>>(
            t, w_rb0_2, rb0_b2, h0, r0, 256, 256);
        mconv<64, 128, 3, 4, true, false><<<dim3(4, 64, 2 * cbn), 256, 0, stream>>>(
            r0, w_rb1_1, rb1_b1, nullptr, t1, 256, 256);
        mconv<64, 128, 1, 4, false, false><<<dim3(4, 64, 2 * cbn), 256, 0, stream>>>(
            r0, w_rb1_s, rb1_bs, nullptr, r1, 256, 256);
        mconv<128, 128, 3, 2, true, true><<<dim3(4, 128, 2 * cbn), 256, 0, stream>>>(
            t1, w_rb1_2, rb1_b2, r1, r1, 256, 256);
        mconv_s2_z<<<dim3(4, 128, 2 * cbn), 256, 0, stream>>>(
            r1, w_down, down_b, z, 256, 256);

        // ---------------- quantizer ----------------
        vq_mfma<<<dim3(cbn * 128), 256, 0, stream>>>(
            z, codebook, cbImg, c2v, qc, partials + (size_t)e0 * 128);
        transpose_q<<<dim3(cbn * 128), 256, 0, stream>>>(qc, qh);

        // ---------------- decoder ----------------
        mconv<128, 128, 3, 2, true, false><<<dim3(2, 64, 2 * cbn), 256, 0, stream>>>(
            qh, w_d1_1, d1_b1, nullptr, dt, 128, 128);
        mconv<128, 128, 3, 2, true, true><<<dim3(2, 64, 2 * cbn), 256, 0, stream>>>(
            dt, w_d1_2, d1_b2, qh, dr, 128, 128);
        upsample2x_nhwc<<<dim3(cbn * 4096), 256, 0, stream>>>(dr, up);
        mconv<128, 64, 3, 2, true, false><<<dim3(4, 128, cbn), 256, 0, stream>>>(
            up, w_up, up_b, nullptr, u, 256, 256);
        mconv<64, 64, 3, 4, true, false><<<dim3(4, 64, cbn), 256, 0, stream>>>(
            u, w_d0_1, d0_b1, nullptr, t2, 256, 256);
        mconv<64, 64, 3, 4, true, true><<<dim3(4, 64, cbn), 256, 0, stream>>>(
            t2, w_d0_2, d0_b2, u, r2, 256, 256);
        mconv_out<<<dim3(4, 64, cbn), 256, 0, stream>>>(
            r2, w_out, out_b, outc, 256, 256);
    }

    // ---------------- loss ----------------
    loss_finish<<<dim3(1), 256, 0, stream>>>(partials, (float*)d_out + 1572864);
}

// Round 9
// 1754.327 us; speedup vs baseline: 1.9003x; 1.0198x over previous
//
#include <hip/hip_runtime.h>

// ---------------------------------------------------------------------------
// VQ-VAE forward: bf16 MFMA implicit-GEMM convs (NHWC) + split-bf16 MFMA VQ.
// R9: ROWS=4 for CIN=128 H=256 stride-1 convs (rb1_2, dec-up): 2:1 MFMA:ds_read
// ratio, 2x thicker barrier windows, halved weight refetch.
// ---------------------------------------------------------------------------

typedef float    f32x4  __attribute__((ext_vector_type(4)));
typedef short    bf16x8 __attribute__((ext_vector_type(8)));
typedef int      i32x4  __attribute__((ext_vector_type(4)));
typedef unsigned short ush;
typedef unsigned long long u64;

__device__ __forceinline__ ush f2bf(float f) {
    unsigned u = __float_as_uint(f);
    u += 0x7fff + ((u >> 16) & 1);          // round-to-nearest-even
    return (ush)(u >> 16);
}
__device__ __forceinline__ float bf2f(ush h) {
    return __uint_as_float(((unsigned)h) << 16);
}
__device__ __forceinline__ i32x4 ntld4(const void* p) {
    return __builtin_nontemporal_load((const i32x4*)p);
}

// XCD-aware swizzle: lin' = (lin%8)*(N/8) + lin/8 (N%8==0 at all call sites),
// decoded y-slowest so each XCD owns a contiguous y-band (x fastest, then z).
__device__ __forceinline__ void swz_coords(int& bx, int& by, int& bz) {
    const int X = gridDim.x, Z = gridDim.z;
    int lin = blockIdx.x + X * (blockIdx.y + gridDim.y * blockIdx.z);
    const int N = X * gridDim.y * Z;
    lin = (lin & 7) * (N >> 3) + (lin >> 3);
    bx = lin % X;
    int r = lin / X;
    bz = r % Z;
    by = r / Z;
}

// ========== weight repack OIHW f32 -> kxy-major bf16 [kxy][o][i] ===========
__global__ void prep_w(const float* __restrict__ src, ush* __restrict__ dst,
                       int O, int I, int KS, int Opad)
{
    int idx = blockIdx.x * 256 + threadIdx.x;
    if (idx >= Opad * KS * KS * I) return;
    int ci  = idx % I;
    int rem = idx / I;
    int o   = rem % Opad;
    int kxy = rem / Opad;
    int kx = kxy % KS, ky = kxy / KS;
    float v = 0.f;
    if (o < O) v = src[((size_t)(o * I + ci) * KS + ky) * KS + kx];
    dst[((size_t)kxy * Opad + o) * I + ci] = f2bf(v);
}

// ============ codebook split hi/lo, pre-swizzled LDS image =================
__global__ void prep_cb_split(const float* __restrict__ cb, char* __restrict__ img)
{
    int idx = blockIdx.x * 256 + threadIdx.x;   // 1024*128
    if (idx >= 1024 * 128) return;
    int k = idx >> 7, e = idx & 127;
    int chunk = k >> 7, cidx = k & 127;
    float c = cb[idx];
    ush hi = f2bf(c);
    ush lo = f2bf(c - bf2f(hi));
    int boff = (((cidx * 128) + e) * 2) ^ ((cidx & 7) << 4);
    char* base = img + (size_t)chunk * 65536;
    *(ush*)(base + boff) = hi;
    *(ush*)(base + boff + 32768) = lo;
}

// ===================== enc_in: 3->64, NCHW f32 in -> NHWC bf16 out =========
__global__ __launch_bounds__(256) void enc_in_k(
    const float* __restrict__ x, const float* __restrict__ w,
    const float* __restrict__ bias, ush* __restrict__ out)
{
    __shared__ float sX[3][3][260];
    __shared__ float sW[27][64];
    __shared__ float sB[64];
    const int tid = threadIdx.x;
    const int y = blockIdx.x, b = blockIdx.y;

    for (int i = tid; i < 3 * 3 * 258; i += 256) {
        int xi = i % 258;
        int r  = (i / 258) % 3;
        int c  = i / 774;
        int gy = y + r - 1, gx = xi - 1;
        float v = 0.f;
        if ((unsigned)gy < 256u && (unsigned)gx < 256u)
            v = x[(((size_t)b * 3 + c) * 256 + gy) * 256 + gx];
        sX[c][r][xi] = v;
    }
    for (int i = tid; i < 1728; i += 256) {
        int co = i & 63, k = i >> 6;
        int c = k % 3, kxy = k / 3;
        int kx = kxy % 3, ky = kxy / 3;
        sW[k][co] = w[co * 27 + c * 9 + ky * 3 + kx];
    }
    if (tid < 64) sB[tid] = bias[tid];
    __syncthreads();

    float acc[64];
#pragma unroll
    for (int c = 0; c < 64; ++c) acc[c] = 0.f;
    const int px = tid;
#pragma unroll
    for (int k = 0; k < 27; ++k) {
        const int c = k % 3, kxy = k / 3;
        const int kx = kxy % 3, ky = kxy / 3;
        float iv = sX[c][ky][px + kx];
#pragma unroll
        for (int co = 0; co < 64; ++co) acc[co] = fmaf(iv, sW[k][co], acc[co]);
    }
    ush* op = out + (((size_t)b * 256 + y) * 256 + px) * 64;
#pragma unroll
    for (int c8 = 0; c8 < 8; ++c8) {
        ush tmp[8];
#pragma unroll
        for (int j = 0; j < 8; ++j) tmp[j] = f2bf(acc[c8 * 8 + j] + sB[c8 * 8 + j]);
        *(int4*)(op + c8 * 8) = *(const int4*)tmp;
    }
}

// ===================== MFMA conv, stride 1, NHWC bf16 ======================
// Block: 64 cout x 64 px x ROWS rows, 4 waves. Per kxy: 8KB weight slab
// double-buffered in LDS (issue-early/write-late); K-loop is LDS-only.
template<int CIN, int COUT, int KS, int ROWS, bool RELU, bool ADD>
__global__ __launch_bounds__(256) void mconv(
    const ush* __restrict__ in, const ush* __restrict__ wt,
    const float* __restrict__ bias, const ush* __restrict__ res,
    ush* __restrict__ out, int H, int W)
{
    constexpr int HALO  = KS / 2;
    constexpr int XW    = 64 + 2 * HALO;
    constexpr int COB   = COUT / 64;
    constexpr int SROWS = ROWS + 2 * HALO;
    constexpr int F     = ROWS;
    constexpr int WPR   = 4 / ROWS;
    constexpr int CP    = (CIN > 64) ? 2 : 1;
    constexpr int CC    = CIN / CP;
    constexpr int KK    = KS * KS;

    __shared__ ush sIn[SROWS * XW * CC];
    __shared__ ush sW[2][64 * CC];

    int bx, by, bz;
    swz_coords(bx, by, bz);
    const int tid = threadIdx.x;
    const int b   = bz / COB;
    const int co0 = (bz % COB) * 64;
    const int y0  = by * ROWS;
    const int x0  = bx * 64;

    const int lane = tid & 63, wid = tid >> 6;
    const int r   = wid / WPR;
    const int fb  = (wid % WPR) * F;
    const int l15 = lane & 15, lq = lane >> 4;

    // this thread's two weight chunks (512 x 16B per slab)
    const int co_a0 = tid >> 3,           ci8_a = tid & 7;
    const int co_b0 = (tid + 256) >> 3,   ci8_b = tid & 7;
    const int wdstA = ((co_a0 * CC + ci8_a * 8) * 2) ^ ((co_a0 & 7) << 4);
    const int wdstB = ((co_b0 * CC + ci8_b * 8) * 2) ^ ((co_b0 & 7) << 4);

    f32x4 acc[4][F] = {};

#pragma unroll 1
    for (int ph = 0; ph < CP; ++ph) {
        if (ph) __syncthreads();
        // ---- input stage (NT loads, XOR swizzle) ----
        constexpr int CHUNKS = SROWS * XW * CC / 8;
        for (int i = tid; i < CHUNKS; i += 256) {
            int ci8 = i % (CC / 8);
            int r2  = i / (CC / 8);
            int xi  = r2 % XW;
            int row = r2 / XW;
            int gy = y0 + row - HALO;
            int gx = x0 + xi - HALO;
            i32x4 v = {0, 0, 0, 0};
            if ((unsigned)gy < (unsigned)H && (unsigned)gx < (unsigned)W)
                v = ntld4(in + (((size_t)b * H + gy) * W + gx) * CIN + ph * CC + ci8 * 8);
            int bo = ((row * XW + xi) * CC + ci8 * 8) * 2;
            *(i32x4*)((char*)sIn + (bo ^ ((xi & 7) << 4))) = v;
        }
        // ---- weight prologue: kxy=0 -> buf0 ----
        {
            const ush* slab = wt + (size_t)co0 * CIN + ph * CC;
            i32x4 v0 = *(const i32x4*)(slab + (size_t)co_a0 * CIN + ci8_a * 8);
            i32x4 v1 = *(const i32x4*)(slab + (size_t)co_b0 * CIN + ci8_b * 8);
            *(i32x4*)((char*)sW[0] + wdstA) = v0;
            *(i32x4*)((char*)sW[0] + wdstB) = v1;
        }
        __syncthreads();

        int curb = 0;
#pragma unroll 1
        for (int kxy = 0; kxy < KK; ++kxy) {
            const int kx = kxy % KS, ky = kxy / KS;
            i32x4 w0, w1;
            const bool hn = (kxy + 1 < KK);
            if (hn) {
                const ush* slab = wt + ((size_t)(kxy + 1) * COUT + co0) * CIN + ph * CC;
                w0 = *(const i32x4*)(slab + (size_t)co_a0 * CIN + ci8_a * 8);
                w1 = *(const i32x4*)(slab + (size_t)co_b0 * CIN + ci8_b * 8);
            }
#pragma unroll
            for (int kb2 = 0; kb2 < CC / 32; ++kb2) {
                const int cip0 = kb2 * 32;
                bf16x8 a[4];
#pragma unroll
                for (int m = 0; m < 4; ++m) {
                    const int coa = m * 16 + l15;
                    a[m] = *(const bf16x8*)((const char*)sW[curb] +
                           (((coa * CC + cip0 + lq * 8) * 2) ^ ((coa & 7) << 4)));
                }
#pragma unroll
                for (int n = 0; n < F; ++n) {
                    const int xi = (fb + n) * 16 + l15 + kx;
                    const int bo = (((r + ky) * XW + xi) * CC + cip0 + lq * 8) * 2;
                    bf16x8 bv = *(const bf16x8*)((const char*)sIn + (bo ^ ((xi & 7) << 4)));
#pragma unroll
                    for (int m = 0; m < 4; ++m)
                        acc[m][n] = __builtin_amdgcn_mfma_f32_16x16x32_bf16(a[m], bv, acc[m][n], 0, 0, 0);
                }
            }
            if (hn) {
                *(i32x4*)((char*)sW[curb ^ 1] + wdstA) = w0;
                *(i32x4*)((char*)sW[curb ^ 1] + wdstB) = w1;
            }
            __syncthreads();
            curb ^= 1;
        }
    }

    const int y = y0 + r;
#pragma unroll
    for (int m = 0; m < 4; ++m) {
        const int com = co0 + m * 16 + lq * 4;
        float4 bvv = *(const float4*)(bias + com);
#pragma unroll
        for (int n = 0; n < F; ++n) {
            const int px = x0 + (fb + n) * 16 + l15;
            size_t oaddr = (((size_t)b * H + y) * W + px) * COUT + com;
            float v0 = acc[m][n][0] + bvv.x;
            float v1 = acc[m][n][1] + bvv.y;
            float v2 = acc[m][n][2] + bvv.z;
            float v3 = acc[m][n][3] + bvv.w;
            if constexpr (ADD) {
                ushort4 rv = *(const ushort4*)(res + oaddr);
                v0 += bf2f(rv.x); v1 += bf2f(rv.y);
                v2 += bf2f(rv.z); v3 += bf2f(rv.w);
            }
            if constexpr (RELU) {
                v0 = fmaxf(v0, 0.f); v1 = fmaxf(v1, 0.f);
                v2 = fmaxf(v2, 0.f); v3 = fmaxf(v3, 0.f);
            }
            ushort4 o;
            o.x = f2bf(v0); o.y = f2bf(v1); o.z = f2bf(v2); o.w = f2bf(v3);
            *(ushort4*)(out + oaddr) = o;
        }
    }
}

// ============ MFMA conv 3x3 stride 2 (128->128), out z NCHW fp32 ===========
__global__ __launch_bounds__(256) void mconv_s2_z(
    const ush* __restrict__ in, const ush* __restrict__ wt,
    const float* __restrict__ bias, float* __restrict__ zout, int Hi, int Wi)
{
    constexpr int CIN = 128, COUT = 128, XW = 66, CC = 64;
    __shared__ ush sIn[3 * XW * CC];
    __shared__ ush sW[2][64 * CC];
    const int Ho = Hi >> 1, Wo = Wi >> 1;
    int bx, by, bz;
    swz_coords(bx, by, bz);
    const int tid = threadIdx.x;
    const int b = bz >> 1, co0 = (bz & 1) * 64;
    const int yo = by, xo0 = bx * 32;

    const int lane = tid & 63, wid = tid >> 6;
    const int wm = wid >> 1, wn = wid & 1;
    const int l15 = lane & 15, lq = lane >> 4;
    const int pxl = wn * 16 + l15;

    const int co_a0 = tid >> 3,         ci8_a = tid & 7;
    const int co_b0 = (tid + 256) >> 3, ci8_b = tid & 7;
    const int wdstA = ((co_a0 * CC + ci8_a * 8) * 2) ^ ((co_a0 & 7) << 4);
    const int wdstB = ((co_b0 * CC + ci8_b * 8) * 2) ^ ((co_b0 & 7) << 4);

    f32x4 acc[2] = {};

#pragma unroll 1
    for (int ph = 0; ph < 2; ++ph) {
        if (ph) __syncthreads();
        for (int i = tid; i < 3 * XW * CC / 8; i += 256) {
            int ci8 = i & 7;
            int r2  = i >> 3;
            int xi  = r2 % XW;
            int row = r2 / XW;
            int gy = 2 * yo + row - 1, gx = 2 * xo0 + xi - 1;
            i32x4 v = {0, 0, 0, 0};
            if ((unsigned)gy < (unsigned)Hi && (unsigned)gx < (unsigned)Wi)
                v = ntld4(in + (((size_t)b * Hi + gy) * Wi + gx) * CIN + ph * CC + ci8 * 8);
            int bo = ((row * XW + xi) * CC + ci8 * 8) * 2;
            *(i32x4*)((char*)sIn + (bo ^ ((xi & 7) << 4))) = v;
        }
        {
            const ush* slab = wt + (size_t)co0 * CIN + ph * CC;
            i32x4 v0 = *(const i32x4*)(slab + (size_t)co_a0 * CIN + ci8_a * 8);
            i32x4 v1 = *(const i32x4*)(slab + (size_t)co_b0 * CIN + ci8_b * 8);
            *(i32x4*)((char*)sW[0] + wdstA) = v0;
            *(i32x4*)((char*)sW[0] + wdstB) = v1;
        }
        __syncthreads();

        int curb = 0;
#pragma unroll 1
        for (int kxy = 0; kxy < 9; ++kxy) {
            const int kx = kxy % 3, ky = kxy / 3;
            i32x4 w0, w1;
            const bool hn = (kxy + 1 < 9);
            if (hn) {
                const ush* slab = wt + ((size_t)(kxy + 1) * COUT + co0) * CIN + ph * CC;
                w0 = *(const i32x4*)(slab + (size_t)co_a0 * CIN + ci8_a * 8);
                w1 = *(const i32x4*)(slab + (size_t)co_b0 * CIN + ci8_b * 8);
            }
#pragma unroll
            for (int kb2 = 0; kb2 < 2; ++kb2) {
                const int cip0 = kb2 * 32;
                bf16x8 a[2];
#pragma unroll
                for (int m = 0; m < 2; ++m) {
                    const int coa = wm * 32 + m * 16 + l15;
                    a[m] = *(const bf16x8*)((const char*)sW[curb] +
                           (((coa * CC + cip0 + lq * 8) * 2) ^ ((coa & 7) << 4)));
                }
                const int xl = 2 * pxl + kx;
                const int bo = ((ky * XW + xl) * CC + cip0 + lq * 8) * 2;
                bf16x8 bfr = *(const bf16x8*)((const char*)sIn + (bo ^ ((xl & 7) << 4)));
                acc[0] = __builtin_amdgcn_mfma_f32_16x16x32_bf16(a[0], bfr, acc[0], 0, 0, 0);
                acc[1] = __builtin_amdgcn_mfma_f32_16x16x32_bf16(a[1], bfr, acc[1], 0, 0, 0);
            }
            if (hn) {
                *(i32x4*)((char*)sW[curb ^ 1] + wdstA) = w0;
                *(i32x4*)((char*)sW[curb ^ 1] + wdstB) = w1;
            }
            __syncthreads();
            curb ^= 1;
        }
    }

    const int px = xo0 + pxl;
#pragma unroll
    for (int m = 0; m < 2; ++m) {
        const int com = co0 + wm * 32 + m * 16 + lq * 4;
        float4 bv = *(const float4*)(bias + com);
#pragma unroll
        for (int r = 0; r < 4; ++r) {
            float v = acc[m][r] + ((const float*)&bv)[r];
            v = fmaxf(v, 0.f);
            zout[(((size_t)b * COUT + com + r) * Ho + yo) * Wo + px] = v;
        }
    }
}

// ============ final conv 64->3, NHWC bf16 in -> NCHW f32 d_out =============
__global__ __launch_bounds__(256) void mconv_out(
    const ush* __restrict__ in, const ush* __restrict__ wt,
    const float* __restrict__ bias, float* __restrict__ outv, int H, int W)
{
    constexpr int K32 = 18, XW = 66, SROWS = 6;
    __shared__ ush sIn[SROWS * XW * 64];
    int bx, by, bz;
    swz_coords(bx, by, bz);
    const int tid = threadIdx.x;
    const int b = bz, y0 = by * 4, x0 = bx * 64;

    for (int i = tid; i < SROWS * XW * 64 / 8; i += 256) {
        int ci8 = i & 7;
        int r2  = i >> 3;
        int xi  = r2 % XW;
        int row = r2 / XW;
        int gy = y0 + row - 1, gx = x0 + xi - 1;
        i32x4 v = {0, 0, 0, 0};
        if ((unsigned)gy < (unsigned)H && (unsigned)gx < (unsigned)W)
            v = ntld4(in + (((size_t)b * H + gy) * W + gx) * 64 + ci8 * 8);
        int bo = ((row * XW + xi) * 64 + ci8 * 8) * 2;
        *(i32x4*)((char*)sIn + (bo ^ ((xi & 7) << 4))) = v;
    }
    __syncthreads();

    const int lane = tid & 63, wid = tid >> 6;
    const int l15 = lane & 15, lq = lane >> 4;
    const int r = wid;

    f32x4 acc[4] = {};

#pragma unroll
    for (int kb = 0; kb < K32; ++kb) {
        const int k0 = kb * 32;
        const int ci0 = k0 % 64;
        const int kxy = k0 / 64;
        const int kx = kxy % 3, ky = kxy / 3;
        // kxy-major layout: [kxy][16][64]
        bf16x8 a0 = *(const bf16x8*)(wt + ((size_t)kxy * 16 + l15) * 64 + ci0 + lq * 8);
#pragma unroll
        for (int n = 0; n < 4; ++n) {
            const int xi = n * 16 + l15 + kx;
            const int bo = (((r + ky) * XW + xi) * 64 + ci0 + lq * 8) * 2;
            bf16x8 bfr = *(const bf16x8*)((const char*)sIn + (bo ^ ((xi & 7) << 4)));
            acc[n] = __builtin_amdgcn_mfma_f32_16x16x32_bf16(a0, bfr, acc[n], 0, 0, 0);
        }
    }

    const int y = y0 + r;
    if (lq == 0) {
#pragma unroll
        for (int n = 0; n < 4; ++n) {
            const int px = x0 + n * 16 + l15;
#pragma unroll
            for (int ch = 0; ch < 3; ++ch)
                outv[(((size_t)b * 3 + ch) * H + y) * W + px] = acc[n][ch] + bias[ch];
        }
    }
}

// ============== q transpose: NCHW bf16 -> NHWC bf16 (C=H=W=128) ============
__global__ __launch_bounds__(256) void transpose_q(
    const ush* __restrict__ qc, ush* __restrict__ qh)
{
    __shared__ ush sT[128][136];
    const int tid = threadIdx.x;
    const int b = blockIdx.x >> 7, h = blockIdx.x & 127;

    for (int i = tid; i < 2048; i += 256) {
        int c = i >> 4, w8 = i & 15;
        int4 v = *(const int4*)(qc + (((size_t)b * 128 + c) * 128 + h) * 128 + w8 * 8);
        const ush* pv = (const ush*)&v;
#pragma unroll
        for (int j = 0; j < 8; ++j) sT[w8 * 8 + j][c] = pv[j];
    }
    __syncthreads();
    for (int i = tid; i < 2048; i += 256) {
        int w = i >> 4, c8 = i & 15;
        int4 v;
        ush* pv = (ush*)&v;
#pragma unroll
        for (int j = 0; j < 8; ++j) pv[j] = sT[w][c8 * 8 + j];
        *(int4*)(qh + (((size_t)b * 128 + h) * 128 + w) * 128 + c8 * 8) = v;
    }
}

// ================= nearest 2x upsample, NHWC bf16 (C=128) ==================
__global__ void upsample2x_nhwc(const ush* __restrict__ in, ush* __restrict__ out)
{
    long idx = (long)blockIdx.x * 256 + threadIdx.x;
    int c8 = (int)(idx & 15);
    int xx = (int)((idx >> 4) & 255);
    int yy = (int)((idx >> 12) & 255);
    int b  = (int)(idx >> 20);
    int4 v = *(const int4*)(in + (((size_t)b * 128 + (yy >> 1)) * 128 + (xx >> 1)) * 128 + c8 * 8);
    *(int4*)(out + (((size_t)b * 256 + yy) * 256 + xx) * 128 + c8 * 8) = v;
}

// ========================= codebook c^2 ====================================
__global__ void cb_transpose(const float* __restrict__ cb, float* __restrict__ cbT)
{
    int idx = blockIdx.x * 256 + threadIdx.x;
    if (idx < 1024 * 128) {
        int k = idx >> 7, e = idx & 127;
        cbT[e * 1024 + k] = cb[idx];
    }
}

__global__ void cb_c2(const float* __restrict__ cbT, float* __restrict__ c2)
{
    int k = blockIdx.x * 256 + threadIdx.x;
    if (k < 1024) {
        float s = 0.f;
        for (int e = 0; e < 128; ++e) {
            float v = cbT[e * 1024 + k];
            s = fmaf(v, v, s);
        }
        c2[k] = s;
    }
}

// ===================== MFMA quantizer ======================================
__global__ __launch_bounds__(256) void vq_mfma(
    const float* __restrict__ z, const float* __restrict__ cb,
    const char* __restrict__ cbImg, const float* __restrict__ c2,
    ush* __restrict__ q, float* __restrict__ partials)
{
    __shared__ ush   sB[32768];        // 64 KB codebook chunk (hi|lo)
    __shared__ float sC2[1024];
    __shared__ float sZ2p[128][2];
    __shared__ float sZ2[128];
    __shared__ int   sIdx[128];
    __shared__ float sRed[4];

    const int tid = threadIdx.x;
    const int wid = tid >> 6, lane = tid & 63;
    const int l15 = lane & 15, lq = lane >> 4;
    const size_t row0 = (size_t)blockIdx.x * 128;

    for (int i = tid; i < 1024; i += 256) sC2[i] = c2[i];

    {
        int row = tid >> 1, half = tid & 1;
        const float* zp = z + (row0 + row) * 128 + half * 64;
        float s = 0.f;
        for (int j = 0; j < 16; ++j) {
            float4 v = *(const float4*)(zp + j * 4);
            s = fmaf(v.x, v.x, s); s = fmaf(v.y, v.y, s);
            s = fmaf(v.z, v.z, s); s = fmaf(v.w, v.w, s);
        }
        sZ2p[row][half] = s;
    }
    __syncthreads();
    if (tid < 128) sZ2[tid] = sZ2p[tid][0] + sZ2p[tid][1];

    bf16x8 ahi[2][4], alo[2][4];
#pragma unroll
    for (int rt = 0; rt < 2; ++rt) {
#pragma unroll
        for (int ks = 0; ks < 4; ++ks) {
            const float* zp = z + (row0 + wid * 32 + rt * 16 + l15) * 128 + ks * 32 + lq * 8;
            float4 v0 = *(const float4*)zp;
            float4 v1 = *(const float4*)(zp + 4);
            float f[8] = {v0.x, v0.y, v0.z, v0.w, v1.x, v1.y, v1.z, v1.w};
            bf16x8 h, l;
#pragma unroll
            for (int j = 0; j < 8; ++j) {
                ush hb = f2bf(f[j]);
                h[j] = (short)hb;
                l[j] = (short)f2bf(f[j] - bf2f(hb));
            }
            ahi[rt][ks] = h; alo[rt][ks] = l;
        }
    }

    u64 bk[2][4];
#pragma unroll
    for (int rt = 0; rt < 2; ++rt)
#pragma unroll
        for (int rg = 0; rg < 4; ++rg) bk[rt][rg] = ~0ull;

#pragma unroll 1
    for (int p = 0; p < 8; ++p) {
        __syncthreads();
        {
            const int4* gsrc = (const int4*)(cbImg + (size_t)p * 65536);
            int4* ldst = (int4*)sB;
#pragma unroll
            for (int it = 0; it < 16; ++it)
                ldst[it * 256 + tid] = gsrc[it * 256 + tid];
        }
        __syncthreads();

        f32x4 acc[2][8] = {};
#pragma unroll
        for (int ks = 0; ks < 4; ++ks) {
#pragma unroll
            for (int ct = 0; ct < 8; ++ct) {
                int cidx = ct * 16 + l15;
                int boff = ((cidx * 128 + ks * 32 + lq * 8) * 2) ^ ((cidx & 7) << 4);
                bf16x8 bh = *(const bf16x8*)((const char*)sB + boff);
                bf16x8 bl = *(const bf16x8*)((const char*)sB + boff + 32768);
#pragma unroll
                for (int rt = 0; rt < 2; ++rt) {
                    acc[rt][ct] = __builtin_amdgcn_mfma_f32_16x16x32_bf16(ahi[rt][ks], bh, acc[rt][ct], 0, 0, 0);
                    acc[rt][ct] = __builtin_amdgcn_mfma_f32_16x16x32_bf16(alo[rt][ks], bh, acc[rt][ct], 0, 0, 0);
                    acc[rt][ct] = __builtin_amdgcn_mfma_f32_16x16x32_bf16(ahi[rt][ks], bl, acc[rt][ct], 0, 0, 0);
                }
            }
        }
#pragma unroll
        for (int rt = 0; rt < 2; ++rt) {
#pragma unroll
            for (int ct = 0; ct < 8; ++ct) {
                int code = p * 128 + ct * 16 + l15;
                float cc = sC2[code];
#pragma unroll
                for (int rg = 0; rg < 4; ++rg) {
                    float z2 = sZ2[wid * 32 + rt * 16 + lq * 4 + rg];
                    float d = (z2 - 2.0f * acc[rt][ct][rg]) + cc;
                    d = fmaxf(d, 0.f);
                    u64 key = ((u64)__float_as_uint(d) << 32) | (unsigned)code;
                    if (key < bk[rt][rg]) bk[rt][rg] = key;
                }
            }
        }
    }

#pragma unroll
    for (int rt = 0; rt < 2; ++rt) {
#pragma unroll
        for (int rg = 0; rg < 4; ++rg) {
            u64 k = bk[rt][rg];
#pragma unroll
            for (int m = 1; m < 16; m <<= 1) {
                u64 o = __shfl_xor(k, m, 64);
                if (o < k) k = o;
            }
            if (l15 == 0)
                sIdx[wid * 32 + rt * 16 + lq * 4 + rg] = (int)(k & 0xffffffffull);
        }
    }
    __syncthreads();

    float lsse = 0.f;
    {
        int row = tid >> 1, half = tid & 1;
        int code = sIdx[row];
        const float* cbrow = cb + (size_t)code * 128 + half * 64;
        const float* zrow  = z + (row0 + row) * 128 + half * 64;
        ush* qrow = q + (row0 + row) * 128 + half * 64;
        for (int j = 0; j < 16; ++j) {
            float4 cv = *(const float4*)(cbrow + j * 4);
            float4 zv = *(const float4*)(zrow + j * 4);
            float d0 = cv.x - zv.x, d1 = cv.y - zv.y;
            float d2 = cv.z - zv.z, d3 = cv.w - zv.w;
            lsse = fmaf(d0, d0, lsse); lsse = fmaf(d1, d1, lsse);
            lsse = fmaf(d2, d2, lsse); lsse = fmaf(d3, d3, lsse);
            ushort4 o;
            o.x = f2bf(zv.x + d0); o.y = f2bf(zv.y + d1);
            o.z = f2bf(zv.z + d2); o.w = f2bf(zv.w + d3);
            *(ushort4*)(qrow + j * 4) = o;
        }
    }
#pragma unroll
    for (int off = 32; off > 0; off >>= 1) lsse += __shfl_down(lsse, off, 64);
    if (lane == 0) sRed[wid] = lsse;
    __syncthreads();
    if (tid == 0) partials[blockIdx.x] = (sRed[0] + sRed[1]) + (sRed[2] + sRed[3]);
}

// ============================ loss finalize ================================
__global__ __launch_bounds__(256) void loss_finish(
    const float* __restrict__ partials, float* __restrict__ outLoss)
{
    __shared__ float sR[256];
    float s = 0.f;
    for (int i = threadIdx.x; i < 1024; i += 256) s += partials[i];
    sR[threadIdx.x] = s;
    __syncthreads();
    for (int st = 128; st > 0; st >>= 1) {
        if (threadIdx.x < st) sR[threadIdx.x] += sR[threadIdx.x + st];
        __syncthreads();
    }
    if (threadIdx.x == 0) {
        float m = sR[0] / 16777216.0f;
        outLoss[0] = m + 0.25f * m;
    }
}

// ============================= launcher ====================================
extern "C" void kernel_launch(void* const* d_in, const int* in_sizes, int n_in,
                              void* d_out, int out_size, void* d_ws, size_t ws_size,
                              hipStream_t stream)
{
    const float* x        = (const float*)d_in[0];
    const float* enc_in_w = (const float*)d_in[1];
    const float* enc_in_b = (const float*)d_in[2];
    const float* rb0_w1   = (const float*)d_in[3];
    const float* rb0_b1   = (const float*)d_in[4];
    const float* rb0_w2   = (const float*)d_in[5];
    const float* rb0_b2   = (const float*)d_in[6];
    const float* rb1_w1   = (const float*)d_in[7];
    const float* rb1_b1   = (const float*)d_in[8];
    const float* rb1_w2   = (const float*)d_in[9];
    const float* rb1_b2   = (const float*)d_in[10];
    const float* rb1_ws   = (const float*)d_in[11];
    const float* rb1_bs   = (const float*)d_in[12];
    const float* down_w   = (const float*)d_in[13];
    const float* down_b   = (const float*)d_in[14];
    const float* codebook = (const float*)d_in[15];
    const float* d1_w1    = (const float*)d_in[16];
    const float* d1_b1    = (const float*)d_in[17];
    const float* d1_w2    = (const float*)d_in[18];
    const float* d1_b2    = (const float*)d_in[19];
    const float* up_w     = (const float*)d_in[20];
    const float* up_b     = (const float*)d_in[21];
    const float* d0_w1    = (const float*)d_in[22];
    const float* d0_b1    = (const float*)d_in[23];
    const float* d0_w2    = (const float*)d_in[24];
    const float* d0_b2    = (const float*)d_in[25];
    const float* out_w    = (const float*)d_in[26];
    const float* out_b    = (const float*)d_in[27];
    (void)in_sizes; (void)n_in; (void)out_size;

    const size_t MB = 1ull << 20;
    char* ws = (char*)d_ws;
    float* partials = (float*)ws;                  // 1024 f32
    float* c2v      = (float*)(ws + 32 * 1024);    // 1024 f32
    float* cbT      = (float*)(ws + 64 * 1024);    // 128x1024 f32 (512 KB)
    char*  cbImg    = ws + 1 * MB;                 // 512 KB split hi/lo image
    ush*   wreg     = (ush*)(ws + 1 * MB + 512 * 1024);

    ush* w_rb0_1 = wreg + 0;
    ush* w_rb0_2 = wreg + 36864;
    ush* w_rb1_1 = wreg + 73728;
    ush* w_rb1_2 = wreg + 147456;
    ush* w_rb1_s = wreg + 294912;
    ush* w_down  = wreg + 303104;
    ush* w_d1_1  = wreg + 450560;
    ush* w_d1_2  = wreg + 598016;
    ush* w_up    = wreg + 745472;
    ush* w_d0_1  = wreg + 819200;
    ush* w_d0_2  = wreg + 856064;
    ush* w_out   = wreg + 892928;

    char* base = ws + 4 * MB;

    int cbn = 8;
    while (cbn > 1 && 4 * MB + (size_t)cbn * 56 * MB > ws_size) cbn >>= 1;

    auto prep = [&](const float* src, ush* dst, int O, int I, int KSp, int Opad) {
        int tot = Opad * KSp * KSp * I;
        prep_w<<<dim3((tot + 255) / 256), 256, 0, stream>>>(src, dst, O, I, KSp, Opad);
    };
    prep(rb0_w1, w_rb0_1, 64, 64, 3, 64);
    prep(rb0_w2, w_rb0_2, 64, 64, 3, 64);
    prep(rb1_w1, w_rb1_1, 128, 64, 3, 128);
    prep(rb1_w2, w_rb1_2, 128, 128, 3, 128);
    prep(rb1_ws, w_rb1_s, 128, 64, 1, 128);
    prep(down_w, w_down, 128, 128, 3, 128);
    prep(d1_w1, w_d1_1, 128, 128, 3, 128);
    prep(d1_w2, w_d1_2, 128, 128, 3, 128);
    prep(up_w, w_up, 64, 128, 3, 64);
    prep(d0_w1, w_d0_1, 64, 64, 3, 64);
    prep(d0_w2, w_d0_2, 64, 64, 3, 64);
    prep(out_w, w_out, 3, 64, 3, 16);

    cb_transpose<<<dim3(512), 256, 0, stream>>>(codebook, cbT);
    cb_c2<<<dim3(4), 256, 0, stream>>>(cbT, c2v);
    prep_cb_split<<<dim3(512), 256, 0, stream>>>(codebook, cbImg);

    for (int e0 = 0; e0 < 8; e0 += cbn) {
        const float* xc   = x + (size_t)e0 * 3 * 65536;
        float*       outc = (float*)d_out + (size_t)e0 * 3 * 65536;

        ush*   h0 = (ush*)(base + (size_t)cbn * 0 * MB);
        ush*   t  = (ush*)(base + (size_t)cbn * 8 * MB);
        ush*   r0 = (ush*)(base + (size_t)cbn * 16 * MB);
        ush*   t1 = (ush*)(base + (size_t)cbn * 24 * MB);
        ush*   r1 = (ush*)(base + (size_t)cbn * 40 * MB);
        float* z  = (float*)(base + (size_t)cbn * 0 * MB);
        ush*   qc = (ush*)(base + (size_t)cbn * 8 * MB);
        ush*   qh = (ush*)(base + (size_t)cbn * 12 * MB);
        ush*   dt = (ush*)(base + (size_t)cbn * 16 * MB);
        ush*   dr = (ush*)(base + (size_t)cbn * 20 * MB);
        ush*   up = (ush*)(base + (size_t)cbn * 24 * MB);
        ush*   u  = (ush*)(base + (size_t)cbn * 40 * MB);
        ush*   t2 = (ush*)(base + (size_t)cbn * 0 * MB);
        ush*   r2 = (ush*)(base + (size_t)cbn * 8 * MB);

        // ---------------- encoder ----------------
        enc_in_k<<<dim3(256, cbn), 256, 0, stream>>>(xc, enc_in_w, enc_in_b, h0);
        mconv<64, 64, 3, 4, true, false><<<dim3(4, 64, cbn), 256, 0, stream>>>(
            h0, w_rb0_1, rb0_b1, nullptr, t, 256, 256);
        mconv<64, 64, 3, 4, true, true><<<dim3(4, 64, cbn), 256, 0, stream>>>(
            t, w_rb0_2, rb0_b2, h0, r0, 256, 256);
        mconv<64, 128, 3, 4, true, false><<<dim3(4, 64, 2 * cbn), 256, 0, stream>>>(
            r0, w_rb1_1, rb1_b1, nullptr, t1, 256, 256);
        mconv<64, 128, 1, 4, false, false><<<dim3(4, 64, 2 * cbn), 256, 0, stream>>>(
            r0, w_rb1_s, rb1_bs, nullptr, r1, 256, 256);
        mconv<128, 128, 3, 4, true, true><<<dim3(4, 64, 2 * cbn), 256, 0, stream>>>(
            t1, w_rb1_2, rb1_b2, r1, r1, 256, 256);
        mconv_s2_z<<<dim3(4, 128, 2 * cbn), 256, 0, stream>>>(
            r1, w_down, down_b, z, 256, 256);

        // ---------------- quantizer ----------------
        vq_mfma<<<dim3(cbn * 128), 256, 0, stream>>>(
            z, codebook, cbImg, c2v, qc, partials + (size_t)e0 * 128);
        transpose_q<<<dim3(cbn * 128), 256, 0, stream>>>(qc, qh);

        // ---------------- decoder ----------------
        mconv<128, 128, 3, 2, true, false><<<dim3(2, 64, 2 * cbn), 256, 0, stream>>>(
            qh, w_d1_1, d1_b1, nullptr, dt, 128, 128);
        mconv<128, 128, 3, 2, true, true><<<dim3(2, 64, 2 * cbn), 256, 0, stream>>>(
            dt, w_d1_2, d1_b2, qh, dr, 128, 128);
        upsample2x_nhwc<<<dim3(cbn * 4096), 256, 0, stream>>>(dr, up);
        mconv<128, 64, 3, 4, true, false><<<dim3(4, 64, cbn), 256, 0, stream>>>(
            up, w_up, up_b, nullptr, u, 256, 256);
        mconv<64, 64, 3, 4, true, false><<<dim3(4, 64, cbn), 256, 0, stream>>>(
            u, w_d0_1, d0_b1, nullptr, t2, 256, 256);
        mconv<64, 64, 3, 4, true, true><<<dim3(4, 64, cbn), 256, 0, stream>>>(
            t2, w_d0_2, d0_b2, u, r2, 256, 256);
        mconv_out<<<dim3(4, 64, cbn), 256, 0, stream>>>(
            r2, w_out, out_b, outc, 256, 256);
    }

    // ---------------- loss ----------------
    loss_finish<<<dim3(1), 256, 0, stream>>>(partials, (float*)d_out + 1572864);
}